// Round 1
// baseline (326.238 us; speedup 1.0000x reference)
//
#include <hip/hip_runtime.h>

typedef unsigned short u16;
typedef unsigned int   u32;
typedef float  f32x4   __attribute__((ext_vector_type(4)));
typedef __bf16 bf16x8  __attribute__((ext_vector_type(8)));
typedef u16    u16x8   __attribute__((ext_vector_type(8)));
typedef u16    u16x4   __attribute__((ext_vector_type(4)));
typedef u32    u32x2   __attribute__((ext_vector_type(2)));
typedef u32    u32x4   __attribute__((ext_vector_type(4)));

#define HIDDEN 2048
#define SEQ    2048
#define NHEADS 16
#define HD     128
#define BATCH  2
#define QSTR   4096   // fused Q|K row stride
#define BK     64
#define NTK    (HIDDEN / BK)   // 32 K-tiles

__device__ __forceinline__ u16 f2bf(float f) {
  u32 u = __builtin_bit_cast(u32, f);
  u += 0x7FFFu + ((u >> 16) & 1u);          // RNE
  return (u16)(u >> 16);
}
__device__ __forceinline__ u32 pk2(float a, float b) {
  __bf16 x = (__bf16)a, y = (__bf16)b;
  return (u32)__builtin_bit_cast(u16, x) | ((u32)__builtin_bit_cast(u16, y) << 16);
}
__device__ __forceinline__ bf16x8 ld_frag(const u16* p) {
  return __builtin_bit_cast(bf16x8, *(const u32x4*)p);
}
__device__ __forceinline__ void gload_lds16(const u16* g, u16* l) {
  __builtin_amdgcn_global_load_lds((const __attribute__((address_space(1))) u32*)g,
                                   (__attribute__((address_space(3))) u32*)l, 16, 0, 0);
}

// ---------------- fp32 -> bf16 convert ----------------
__global__ __launch_bounds__(256) void cvt_kernel(const float* __restrict__ src,
                                                  u16* __restrict__ dst, int n4) {
  int stride = gridDim.x * blockDim.x;
  for (int i = blockIdx.x * blockDim.x + threadIdx.x; i < n4; i += stride) {
    f32x4 v = ((const f32x4*)src)[i];
    u16x4 o;
    o[0] = f2bf(v[0]); o[1] = f2bf(v[1]); o[2] = f2bf(v[2]); o[3] = f2bf(v[3]);
    *(u16x4*)(dst + (size_t)i * 4) = o;
  }
}

__global__ __launch_bounds__(256) void cvt4_kernel(
    const float* __restrict__ s0, const float* __restrict__ s1,
    const float* __restrict__ s2, const float* __restrict__ s3,
    u16* __restrict__ o0, u16* __restrict__ o1,
    u16* __restrict__ o2, u16* __restrict__ o3, int n4) {
  const float* src = (blockIdx.y == 0) ? s0 : (blockIdx.y == 1) ? s1 : (blockIdx.y == 2) ? s2 : s3;
  u16* dst = (blockIdx.y == 0) ? o0 : (blockIdx.y == 1) ? o1 : (blockIdx.y == 2) ? o2 : o3;
  int stride = gridDim.x * blockDim.x;
  for (int i = blockIdx.x * blockDim.x + threadIdx.x; i < n4; i += stride) {
    f32x4 v = ((const f32x4*)src)[i];
    u16x4 o;
    o[0] = f2bf(v[0]); o[1] = f2bf(v[1]); o[2] = f2bf(v[2]); o[3] = f2bf(v[3]);
    *(u16x4*)(dst + (size_t)i * 4) = o;
  }
}

// ---------------- fused QKV projection: 256x256 tile, BK=64, 8-wave, counted-vmcnt pipeline ----------------
// LDS layout per operand tile [256 rows][64 cols bf16], row = 128 B = 8 chunks of 16 B.
// Swizzle: chunk stored at (c ^ (row&7)) -> ds_read_b128 fragment reads are bank-conflict-free.
// Staging pre-swizzles the GLOBAL source (global_load_lds dest must stay linear).
// Schedule per K-tile t (buf = t&1):
//   ph1: ds_read k0 frags (12) | bar | 16 MFMA (k0, N-half0) | bar
//   ph2: ds_read k1 frags (12) | bar | 16 MFMA (k0, N-half1) | lgkmcnt(0) | bar
//   ph3: stage A-halves of t+2 (4 gload_lds) | bar | 16 MFMA (k1, N-half0) | bar
//   ph4: stage B-halves of t+2 (4) | vmcnt(8) | bar | 16 MFMA (k1, N-half1) | bar
// vmcnt(8) leaves exactly tile t+2's 8 loads in flight; tile t+1 is guaranteed landed.
// Reads of buf complete (lgkmcnt 0) before any wave can issue the ph3/ph4 overwriting stages.
__global__ __launch_bounds__(512, 1) void gemm_qkv(
    const u16* __restrict__ A, const u16* __restrict__ Bt,
    const float* __restrict__ bq, const float* __restrict__ bk,
    const float* __restrict__ bv,
    u16* __restrict__ qk, u16* __restrict__ vtb, float qscale)
{
  __shared__ __attribute__((aligned(16))) u16 As[2][16384];  // 64 KiB
  __shared__ __attribute__((aligned(16))) u16 Bs[2][16384];  // 64 KiB

  const int tid  = threadIdx.x;
  const int lane = tid & 63;
  const int wave = tid >> 6;
  const int l15  = lane & 15;
  const int g    = lane >> 4;
  const int wm   = wave >> 2;            // 0..1 (M half)
  const int wn   = wave & 3;             // 0..3 (N quarter)

  // grid 384 = 8 XCD * (3 Ntiles * 16 Mtiles); bijective, B-panels L2-resident per XCD
  const int id  = blockIdx.x;
  const int xcd = id & 7;
  const int c   = id >> 3;               // 0..47
  const int tileN = (xcd * 3 + (c >> 4)) << 8;
  const int tileM = (c & 15) << 8;

  // staging: thread covers row (tid>>3) of each 64-row round, chunk (tid&7)
  const int srow = tid >> 3;
  const int gch8 = ((tid & 7) ^ (srow & 7)) * 8;     // pre-swizzled global chunk
  const u16* agp = A  + (size_t)(tileM + srow) * HIDDEN + gch8;
  const u16* bgp = Bt + (size_t)(tileN + srow) * HIDDEN + gch8;
  u16* asp = &As[0][0] + tid * 8;
  u16* bsp = &Bs[0][0] + tid * 8;

  // fragment read bases: row = (wm*128 + mf*16 + l15), chunk = (kfrag*4+g) ^ (l15&7)
  const int sw = l15 & 7;
  const int offk0 = ((g ^ sw) * 8);
  const int offk1 = (((g + 4) ^ sw) * 8);
  const u16* afr = &As[0][0] + (wm * 128 + l15) * 64;
  const u16* bfr = &Bs[0][0] + (wn * 64 + l15) * 64;

  f32x4 acc[8][4] = {};

  // ---- prologue: stage tiles 0 (buf0) and 1 (buf1); 16 loads, drain to 8
#pragma unroll
  for (int tt = 0; tt < 2; ++tt) {
    const int ko = tt * BK;
    const int lb = tt * 16384;
#pragma unroll
    for (int h = 0; h < 2; ++h)
#pragma unroll
      for (int i = 0; i < 2; ++i) {
        gload_lds16(agp + (size_t)(h * 128 + i * 64) * HIDDEN + ko, asp + lb + h * 8192 + i * 4096);
        gload_lds16(bgp + (size_t)(h * 128 + i * 64) * HIDDEN + ko, bsp + lb + h * 8192 + i * 4096);
      }
  }
  asm volatile("s_waitcnt vmcnt(8)" ::: "memory");
  __builtin_amdgcn_s_barrier();

  for (int t = 0; t < NTK; ++t) {
    const int buf = t & 1;
    const u16* af = afr + buf * 16384;
    const u16* bf = bfr + buf * 16384;
    bf16x8 a0[8], b0[4], a1[8], b1[4];

    // ---------- phase 1: read k0 frags ; MFMA (k0, N-half 0)
#pragma unroll
    for (int mf = 0; mf < 8; ++mf) a0[mf] = ld_frag(af + mf * 1024 + offk0);
#pragma unroll
    for (int nf = 0; nf < 4; ++nf) b0[nf] = ld_frag(bf + nf * 1024 + offk0);
    __builtin_amdgcn_s_barrier();
    __builtin_amdgcn_s_setprio(1);
#pragma unroll
    for (int mf = 0; mf < 8; ++mf)
#pragma unroll
      for (int nf = 0; nf < 2; ++nf)
        acc[mf][nf] = __builtin_amdgcn_mfma_f32_16x16x32_bf16(a0[mf], b0[nf], acc[mf][nf], 0, 0, 0);
    __builtin_amdgcn_s_setprio(0);
    __builtin_amdgcn_s_barrier();

    // ---------- phase 2: read k1 frags ; MFMA (k0, N-half 1)
#pragma unroll
    for (int mf = 0; mf < 8; ++mf) a1[mf] = ld_frag(af + mf * 1024 + offk1);
#pragma unroll
    for (int nf = 0; nf < 4; ++nf) b1[nf] = ld_frag(bf + nf * 1024 + offk1);
    __builtin_amdgcn_s_barrier();
    __builtin_amdgcn_s_setprio(1);
#pragma unroll
    for (int mf = 0; mf < 8; ++mf)
#pragma unroll
      for (int nf = 2; nf < 4; ++nf)
        acc[mf][nf] = __builtin_amdgcn_mfma_f32_16x16x32_bf16(a0[mf], b0[nf], acc[mf][nf], 0, 0, 0);
    __builtin_amdgcn_s_setprio(0);
    asm volatile("s_waitcnt lgkmcnt(0)" ::: "memory");   // all reads of this buf complete
    __builtin_amdgcn_s_barrier();
    __builtin_amdgcn_sched_barrier(0);                   // pin stages strictly after the barrier

    // ---------- phase 3: stage A-halves of tile t+2 ; MFMA (k1, N-half 0)
    const bool pf = (t + 2 < NTK);
    const int ko = (t + 2) * BK;
    const int lb = buf * 16384;
    if (pf) {
#pragma unroll
      for (int h = 0; h < 2; ++h)
#pragma unroll
        for (int i = 0; i < 2; ++i)
          gload_lds16(agp + (size_t)(h * 128 + i * 64) * HIDDEN + ko, asp + lb + h * 8192 + i * 4096);
    }
    __builtin_amdgcn_s_barrier();
    __builtin_amdgcn_s_setprio(1);
#pragma unroll
    for (int mf = 0; mf < 8; ++mf)
#pragma unroll
      for (int nf = 0; nf < 2; ++nf)
        acc[mf][nf] = __builtin_amdgcn_mfma_f32_16x16x32_bf16(a1[mf], b1[nf], acc[mf][nf], 0, 0, 0);
    __builtin_amdgcn_s_setprio(0);
    __builtin_amdgcn_s_barrier();

    // ---------- phase 4: stage B-halves ; counted vmcnt ; MFMA (k1, N-half 1)
    if (pf) {
#pragma unroll
      for (int h = 0; h < 2; ++h)
#pragma unroll
        for (int i = 0; i < 2; ++i)
          gload_lds16(bgp + (size_t)(h * 128 + i * 64) * HIDDEN + ko, bsp + lb + h * 8192 + i * 4096);
      asm volatile("s_waitcnt vmcnt(8)" ::: "memory");   // tile t+1 landed; t+2 in flight
    } else {
      asm volatile("s_waitcnt vmcnt(0)" ::: "memory");   // epilogue drain
    }
    __builtin_amdgcn_s_barrier();
    __builtin_amdgcn_s_setprio(1);
#pragma unroll
    for (int mf = 0; mf < 8; ++mf)
#pragma unroll
      for (int nf = 2; nf < 4; ++nf)
        acc[mf][nf] = __builtin_amdgcn_mfma_f32_16x16x32_bf16(a1[mf], b1[nf], acc[mf][nf], 0, 0, 0);
    __builtin_amdgcn_s_setprio(0);
    __builtin_amdgcn_s_barrier();
  }

  // ---------- epilogue: Q|K -> qk (scaled, biased), V -> transposed vtb
  const int seg = tileN >> 11;                       // 0=Q 1=K 2=V
  const float* bp = (seg == 0) ? bq : (seg == 1) ? bk : bv;
  const float scl = (seg == 0) ? qscale : 1.f;

#pragma unroll
  for (int mi = 0; mi < 8; ++mi) {
#pragma unroll
    for (int ni = 0; ni < 4; ++ni) {
      const int gc = tileN + wn * 64 + ni * 16 + l15;
      const float bvv = bp[gc & 2047];
      if (seg < 2) {
#pragma unroll
        for (int j = 0; j < 4; ++j) {
          const int gr = tileM + wm * 128 + mi * 16 + g * 4 + j;
          qk[(size_t)gr * QSTR + gc] = f2bf((acc[mi][ni][j] + bvv) * scl);
        }
      } else {
        const int dglob = gc - 4096;
        const int hh = dglob >> 7, dd = dglob & 127;
        const int srow0 = tileM + wm * 128 + mi * 16 + g * 4;
        const int bb = srow0 >> 11, ss = srow0 & 2047;
        u16x4 o;
#pragma unroll
        for (int j = 0; j < 4; ++j) o[j] = f2bf(acc[mi][ni][j] + bvv);
        *(u16x4*)(vtb + ((size_t)((bb * NHEADS + hh) * HD + dd)) * SEQ + ss) = o;
      }
    }
  }
}

// ---------------- C = A[M,K] * Bt[N,K]^T + bias (output projection, proven 2-phase) ----------------
__global__ __launch_bounds__(256, 2) void gemm_bt(
    const u16* __restrict__ A, const u16* __restrict__ Bt,
    const float* __restrict__ bias, float* __restrict__ Cout,
    int M, int N, int K)
{
  __shared__ __attribute__((aligned(16))) u16 As[128 * 32];
  __shared__ __attribute__((aligned(16))) u16 Bs[128 * 32];
  const int tid  = threadIdx.x;
  const int lane = tid & 63;
  const int wave = tid >> 6;

  const int nbx   = N >> 7;
  const int nby   = M >> 7;
  const int id    = blockIdx.x;
  const int xcd   = id & 7;
  const int c     = id >> 3;
  const int cpx   = nbx >> 3;
  const int tileN = (xcd * cpx + c / nby) << 7;
  const int tileM = (c % nby) << 7;

  const int g = lane >> 4, r = lane & 15;

  const int srow = lane >> 2;
  const int scol = (lane & 3) * 8;
  const u16* ag0 = A  + (size_t)(tileM + wave * 16 + srow) * K + scol;
  const u16* ag1 = ag0 + (size_t)64 * K;
  const u16* bg0 = Bt + (size_t)(tileN + wave * 16 + srow) * K + scol;
  const u16* bg1 = bg0 + (size_t)64 * K;
  u16* as0 = &As[wave * 512];
  u16* as1 = &As[(wave + 4) * 512];
  u16* bs0 = &Bs[wave * 512];
  u16* bs1 = &Bs[(wave + 4) * 512];

  const int wm = wave >> 1, wn = wave & 1;
  const u16* afp = &As[(wm * 64 + r) * 32 + g * 8];
  const u16* bfp = &Bs[(wn * 64 + r) * 32 + g * 8];

  f32x4 acc[4][4] = {};

  for (int kt = 0; kt < K; kt += 32) {
    __syncthreads();
    gload_lds16(ag0 + kt, as0);
    gload_lds16(ag1 + kt, as1);
    gload_lds16(bg0 + kt, bs0);
    gload_lds16(bg1 + kt, bs1);
    __syncthreads();
    bf16x8 af[4], bf[4];
#pragma unroll
    for (int mi = 0; mi < 4; mi++) af[mi] = ld_frag(afp + mi * 512);
#pragma unroll
    for (int ni = 0; ni < 4; ni++) bf[ni] = ld_frag(bfp + ni * 512);
#pragma unroll
    for (int mi = 0; mi < 4; mi++)
#pragma unroll
      for (int ni = 0; ni < 4; ni++)
        acc[mi][ni] = __builtin_amdgcn_mfma_f32_16x16x32_bf16(af[mi], bf[ni], acc[mi][ni], 0, 0, 0);
  }

#pragma unroll
  for (int mi = 0; mi < 4; mi++) {
#pragma unroll
    for (int ni = 0; ni < 4; ni++) {
      const int gc = tileN + wn * 64 + ni * 16 + r;
      const float bv = bias[gc];
#pragma unroll
      for (int j = 0; j < 4; j++) {
        const int gr = tileM + wm * 64 + mi * 16 + g * 4 + j;
        Cout[(size_t)gr * N + gc] = acc[mi][ni][j] + bv;
      }
    }
  }
}

// ---------------- flash attention: 16x16 MFMA, 32q/wave (2 q-groups), zero-shuffle PV ----------------
__global__ __launch_bounds__(256, 2) void attn_kernel(
    const u16* __restrict__ QKg, const u16* __restrict__ Vtg, u16* __restrict__ Ctx)
{
  __shared__ __attribute__((aligned(16))) u16 Ks[2][32 * 128]; // [kv][16B-unit ^ m(kv)]
  __shared__ __attribute__((aligned(16))) u16 Vs[2][128 * 32]; // [d][kv] linear

  const int tid  = threadIdx.x;
  const int lane = tid & 63;
  const int wave = tid >> 6;
  const int g4   = lane >> 4;
  const int l15  = lane & 15;

  const int wg = ((blockIdx.x & 7) << 6) + (blockIdx.x >> 3);
  const int bh = wg >> 4;                 // 16 blocks per (b,h)
  const int qt = wg & 15;
  const int b  = bh >> 4, h = bh & 15;

  const u16* Qb  = QKg + (size_t)b * SEQ * QSTR + (size_t)h * HD;
  const u16* Kb  = Qb + 2048;
  const u16* Vth = Vtg + (size_t)bh * HD * SEQ;
  u16* Cb = Ctx + (size_t)b * SEQ * HIDDEN + (size_t)h * HD;

  const int qbase = qt * 128 + wave * 32 + l15;

  bf16x8 qf[2][4];
#pragma unroll
  for (int qs = 0; qs < 2; qs++)
#pragma unroll
    for (int dc = 0; dc < 4; dc++)
      qf[qs][dc] = ld_frag(Qb + (size_t)(qbase + qs * 16) * QSTR + dc * 32 + g4 * 8);

  const int kvp0 = (l15 >> 2) * 8 + (l15 & 3);
  const int msw  = (l15 & 3) | (((l15 >> 2) & 1) << 2);

  f32x4 ctx[2][8] = {};
  float m_run[2] = {-1e30f, -1e30f};
  float l_run[2] = {0.f, 0.f};

  auto stage = [&](int buf, int kv0) {
#pragma unroll
    for (int i = 0; i < 2; i++) {
      const int idx = tid + i * 256;
      const int kv = idx >> 4, up = idx & 15;
      const int um = up ^ ((kv & 3) | (((kv >> 3) & 1) << 2));
      gload_lds16(Kb + (size_t)(kv0 + kv) * QSTR + um * 8, &Ks[buf][idx * 8]);
      const int d = idx >> 2, u = idx & 3;
      gload_lds16(Vth + (size_t)d * SEQ + kv0 + u * 8, &Vs[buf][idx * 8]);
    }
  };

  stage(0, 0);
  __syncthreads();

  const int NT = SEQ / 32;
  for (int t = 0; t < NT; t++) {
    const int buf = t & 1;
    if (t + 1 < NT) stage(buf ^ 1, (t + 1) * 32);

    f32x4 s[2][2] = {};
    __builtin_amdgcn_s_setprio(1);
#pragma unroll
    for (int ni = 0; ni < 2; ni++) {
      const int row = kvp0 + ni * 4;
#pragma unroll
      for (int dc = 0; dc < 4; dc++) {
        bf16x8 kf = ld_frag(&Ks[buf][row * 128 + (((dc * 4 + g4) ^ msw) * 8)]);
        s[0][ni] = __builtin_amdgcn_mfma_f32_16x16x32_bf16(kf, qf[0][dc], s[0][ni], 0, 0, 0);
        s[1][ni] = __builtin_amdgcn_mfma_f32_16x16x32_bf16(kf, qf[1][dc], s[1][ni], 0, 0, 0);
      }
    }
    __builtin_amdgcn_s_setprio(0);

    bool ok0, ok1;
    float pmax[2];
#pragma unroll
    for (int qs = 0; qs < 2; qs++) {
      pmax[qs] = fmaxf(fmaxf(fmaxf(s[qs][0][0], s[qs][0][1]), fmaxf(s[qs][0][2], s[qs][0][3])),
                       fmaxf(fmaxf(s[qs][1][0], s[qs][1][1]), fmaxf(s[qs][1][2], s[qs][1][3])));
      pmax[qs] = fmaxf(pmax[qs], __shfl_xor(pmax[qs], 16));
      pmax[qs] = fmaxf(pmax[qs], __shfl_xor(pmax[qs], 32));
    }
    ok0 = (pmax[0] <= m_run[0] + 8.f);
    ok1 = (pmax[1] <= m_run[1] + 8.f);
    if (!__all(ok0 && ok1)) {
#pragma unroll
      for (int qs = 0; qs < 2; qs++) {
        const float mn = fmaxf(m_run[qs], pmax[qs]);
        const float corr = exp2f(m_run[qs] - mn);
        m_run[qs] = mn;
        l_run[qs] *= corr;
#pragma unroll
        for (int dt = 0; dt < 8; dt++)
#pragma unroll
          for (int j = 0; j < 4; j++) ctx[qs][dt][j] *= corr;
      }
    }
    bf16x8 pfrag[2];
#pragma unroll
    for (int qs = 0; qs < 2; qs++) {
      float ps = 0.f;
#pragma unroll
      for (int ni = 0; ni < 2; ni++)
#pragma unroll
        for (int j = 0; j < 4; j++) {
          const float p = exp2f(s[qs][ni][j] - m_run[qs]);
          s[qs][ni][j] = p;
          ps += p;
        }
      ps += __shfl_xor(ps, 16);
      ps += __shfl_xor(ps, 32);
      l_run[qs] += ps;
      u32x4 pw;
      pw[0] = pk2(s[qs][0][0], s[qs][0][1]);
      pw[1] = pk2(s[qs][0][2], s[qs][0][3]);
      pw[2] = pk2(s[qs][1][0], s[qs][1][1]);
      pw[3] = pk2(s[qs][1][2], s[qs][1][3]);
      pfrag[qs] = __builtin_bit_cast(bf16x8, pw);
    }

    __builtin_amdgcn_s_setprio(1);
#pragma unroll
    for (int dt = 0; dt < 8; dt++) {
      bf16x8 vf = ld_frag(&Vs[buf][(dt * 16 + l15) * 32 + g4 * 8]);
      ctx[0][dt] = __builtin_amdgcn_mfma_f32_16x16x32_bf16(vf, pfrag[0], ctx[0][dt], 0, 0, 0);
      ctx[1][dt] = __builtin_amdgcn_mfma_f32_16x16x32_bf16(vf, pfrag[1], ctx[1][dt], 0, 0, 0);
    }
    __builtin_amdgcn_s_setprio(0);

    __syncthreads();
  }

#pragma unroll
  for (int qs = 0; qs < 2; qs++) {
    const float linv = 1.f / l_run[qs];
    u16* crow = Cb + (size_t)(qbase + qs * 16) * HIDDEN;
#pragma unroll
    for (int dt = 0; dt < 8; dt++) {
      u16x4 o;
#pragma unroll
      for (int j = 0; j < 4; j++) o[j] = f2bf(ctx[qs][dt][j] * linv);
      *(u16x4*)&crow[dt * 16 + g4 * 4] = o;
    }
  }
}

// ---------------- launch ----------------
extern "C" void kernel_launch(void* const* d_in, const int* in_sizes, int n_in,
                              void* d_out, int out_size, void* d_ws, size_t ws_size,
                              hipStream_t stream) {
  (void)in_sizes; (void)n_in; (void)out_size; (void)ws_size;
  const float* x  = (const float*)d_in[0];
  const float* wq = (const float*)d_in[1];
  const float* bq = (const float*)d_in[2];
  const float* wk = (const float*)d_in[3];
  const float* bk = (const float*)d_in[4];
  const float* wv = (const float*)d_in[5];
  const float* bv = (const float*)d_in[6];
  const float* wo = (const float*)d_in[7];
  const float* bo = (const float*)d_in[8];

  const size_t NX = (size_t)BATCH * SEQ * HIDDEN;   // 8.39M
  const size_t NW = (size_t)HIDDEN * HIDDEN;        // 4.19M
  u16* xb   = (u16*)d_ws;            // [NX]
  u16* wqb  = xb  + NX;              // [3NW] contiguous Wq|Wk|Wv
  u16* wkb  = wqb + NW;
  u16* wvb  = wkb + NW;
  u16* wob  = wvb + NW;              // [NW]
  u16* qk   = wob + NW;              // [M,4096] fused Q|K
  u16* vtb  = qk  + 2 * NX;          // [B*H, D, S]
  u16* ctxb = xb;                    // x dead after projections

  cvt_kernel<<<2048, 256, 0, stream>>>(x, xb, (int)(NX / 4));
  cvt4_kernel<<<dim3(512, 4), 256, 0, stream>>>(wq, wk, wv, wo, wqb, wkb, wvb, wob, (int)(NW / 4));

  // 1/sqrt(128) * log2(e): scores in log2 units
  const float qscale = 0.12751744174240807f;
  gemm_qkv<<<384, 512, 0, stream>>>(xb, wqb, bq, bk, bv, qk, vtb, qscale);

  attn_kernel<<<512, 256, 0, stream>>>(qk, vtb, ctxb);

  gemm_bt<<<512, 256, 0, stream>>>(ctxb, wob, bo, (float*)d_out, BATCH * SEQ, HIDDEN, HIDDEN);
}

// Round 2
// 289.640 us; speedup vs baseline: 1.1264x; 1.1264x over previous
//
#include <hip/hip_runtime.h>

typedef unsigned short u16;
typedef unsigned int   u32;
typedef float  f32x4   __attribute__((ext_vector_type(4)));
typedef __bf16 bf16x8  __attribute__((ext_vector_type(8)));
typedef u16    u16x8   __attribute__((ext_vector_type(8)));
typedef u16    u16x4   __attribute__((ext_vector_type(4)));
typedef u32    u32x2   __attribute__((ext_vector_type(2)));
typedef u32    u32x4   __attribute__((ext_vector_type(4)));

#define HIDDEN 2048
#define SEQ    2048
#define NHEADS 16
#define HD     128
#define BATCH  2
#define QSTR   4096   // fused Q|K row stride

typedef const __attribute__((address_space(3))) u16* lptr;

__device__ __forceinline__ u16 f2bf(float f) {
  u32 u = __builtin_bit_cast(u32, f);
  u += 0x7FFFu + ((u >> 16) & 1u);          // RNE
  return (u16)(u >> 16);
}
__device__ __forceinline__ u32 pk2(float a, float b) {
  __bf16 x = (__bf16)a, y = (__bf16)b;
  return (u32)__builtin_bit_cast(u16, x) | ((u32)__builtin_bit_cast(u16, y) << 16);
}
__device__ __forceinline__ bf16x8 ld_frag(const u16* p) {
  return __builtin_bit_cast(bf16x8, *(const u32x4*)p);
}
__device__ __forceinline__ void gload_lds16(const u16* g, u16* l) {
  __builtin_amdgcn_global_load_lds((const __attribute__((address_space(1))) u32*)g,
                                   (__attribute__((address_space(3))) u32*)l, 16, 0, 0);
}

// inline-asm LDS read: compiler inserts no auto-waits; we count lgkmcnt manually.
#define DSR(dst, base, lit) \
  asm volatile("ds_read_b128 %0, %1 offset:" lit : "=v"(dst) : "v"(base))

// ---------------- fp32 -> bf16 convert ----------------
__global__ __launch_bounds__(256) void cvt_kernel(const float* __restrict__ src,
                                                  u16* __restrict__ dst, int n4) {
  int stride = gridDim.x * blockDim.x;
  for (int i = blockIdx.x * blockDim.x + threadIdx.x; i < n4; i += stride) {
    f32x4 v = ((const f32x4*)src)[i];
    u16x4 o;
    o[0] = f2bf(v[0]); o[1] = f2bf(v[1]); o[2] = f2bf(v[2]); o[3] = f2bf(v[3]);
    *(u16x4*)(dst + (size_t)i * 4) = o;
  }
}

__global__ __launch_bounds__(256) void cvt4_kernel(
    const float* __restrict__ s0, const float* __restrict__ s1,
    const float* __restrict__ s2, const float* __restrict__ s3,
    u16* __restrict__ o0, u16* __restrict__ o1,
    u16* __restrict__ o2, u16* __restrict__ o3, int n4) {
  const float* src = (blockIdx.y == 0) ? s0 : (blockIdx.y == 1) ? s1 : (blockIdx.y == 2) ? s2 : s3;
  u16* dst = (blockIdx.y == 0) ? o0 : (blockIdx.y == 1) ? o1 : (blockIdx.y == 2) ? o2 : o3;
  int stride = gridDim.x * blockDim.x;
  for (int i = blockIdx.x * blockDim.x + threadIdx.x; i < n4; i += stride) {
    f32x4 v = ((const f32x4*)src)[i];
    u16x4 o;
    o[0] = f2bf(v[0]); o[1] = f2bf(v[1]); o[2] = f2bf(v[2]); o[3] = f2bf(v[3]);
    *(u16x4*)(dst + (size_t)i * 4) = o;
  }
}

// ---------------- fused QKV projection: 256Mx192N tile, BK=64, 8-wave, asm-counted pipeline ----------------
// 512 blocks (16M x 32N) = exactly 2 full rounds on 256 CUs. LDS 112 KiB, 1 block/CU.
// LDS tiles: A [256][64] bf16 (32KB), B [192][64] (24KB), x2 double-buffer.
// Swizzle: 16B chunk c of row r stored at c^(r&7); staging pre-swizzles GLOBAL source.
// Per K-tile t (cur=t&1), frag sets X=(cur,k0) issued previous tail, Y=(cur,k1):
//  [1] issue Y (11 asm ds_read_b128)
//  [2] lgkmcnt(11) -> X ready (Y stays in flight); 24 MFMA on X
//  [3] lgkmcnt(0)  -> Y ready;                     24 MFMA on Y
//  [4] barrier (all waves done reading cur)
//  [5] stage t+2 -> cur (7 global_load_lds)
//  [6] vmcnt(7): own t+1 landed, t+2 in flight; barrier (ALL waves' t+1 landed)
//  [7] issue X' = (nxt, k0)
__global__ __launch_bounds__(512, 2) void gemm_qkv(
    const u16* __restrict__ A, const u16* __restrict__ Bt,
    const float* __restrict__ bq, const float* __restrict__ bk,
    const float* __restrict__ bv,
    u16* __restrict__ qk, u16* __restrict__ vtb, float qscale)
{
  __shared__ __attribute__((aligned(16))) u16 As[2][16384];  // 64 KiB
  __shared__ __attribute__((aligned(16))) u16 Bs[2][12288];  // 48 KiB

  const int tid  = threadIdx.x;
  const int lane = tid & 63;
  const int wave = tid >> 6;
  const int l15  = lane & 15;
  const int g    = lane >> 4;
  const int wm   = wave >> 2;            // 0..1 (M half, 128 rows)
  const int wn   = wave & 3;             // 0..3 (N quarter, 48 cols)

  // grid 512 = 8 XCD * (4 Ntiles * 16 Mtiles); bijective, 4 B-panels (3MB) L2-resident per XCD
  const int id  = blockIdx.x;
  const int xcd = id & 7;
  const int c   = id >> 3;               // 0..63
  const int tileN = (xcd * 4 + (c >> 4)) * 192;
  const int tileM = (c & 15) << 8;

  // staging: thread covers row (tid>>3) of each 64-row round, chunk (tid&7)
  const int srow = tid >> 3;
  const int gch8 = ((tid & 7) ^ (srow & 7)) * 8;     // pre-swizzled global chunk
  const u16* agp = A  + (size_t)(tileM + srow) * HIDDEN + gch8;
  const u16* bgp = Bt + (size_t)(tileN + srow) * HIDDEN + gch8;
  u16* asp = (u16*)&As[0][0] + tid * 8;
  u16* bsp = (u16*)&Bs[0][0] + tid * 8;

  auto stage = [&](int buf, int ko) {
    u16* ad = asp + buf * 16384;
    u16* bd = bsp + buf * 12288;
#pragma unroll
    for (int r = 0; r < 4; ++r)
      gload_lds16(agp + (size_t)r * 64 * HIDDEN + ko, ad + r * 4096);
#pragma unroll
    for (int r = 0; r < 3; ++r)
      gload_lds16(bgp + (size_t)r * 64 * HIDDEN + ko, bd + r * 4096);
  };

  // fragment read bases (asm, byte offsets in literals): row stride 16 rows = 2048 B
  const int sw = l15 & 7;
  const int c0 = (g ^ sw) * 8;           // k0 chunk (elements)
  const int c1 = ((g ^ sw) ^ 4) * 8;     // k1 chunk
  lptr aT = (lptr)&As[0][0] + (size_t)(wm * 128 + l15) * 64;
  lptr bT = (lptr)&Bs[0][0] + (size_t)(wn * 48 + l15) * 64;

  f32x4 acc[8][3] = {};
  bf16x8 Xa[8], Xb[3], Ya[8], Yb[3];

#define ISSUE_SET(Sa, Sb, ab, bb)      \
  DSR(Sa[0], ab, "0");                 \
  DSR(Sa[1], ab, "2048");              \
  DSR(Sa[2], ab, "4096");              \
  DSR(Sa[3], ab, "6144");              \
  DSR(Sa[4], ab, "8192");              \
  DSR(Sa[5], ab, "10240");             \
  DSR(Sa[6], ab, "12288");             \
  DSR(Sa[7], ab, "14336");             \
  DSR(Sb[0], bb, "0");                 \
  DSR(Sb[1], bb, "2048");              \
  DSR(Sb[2], bb, "4096");

#define MFMA24(Sa, Sb)                                                                    \
  _Pragma("unroll")                                                                       \
  for (int mf = 0; mf < 8; ++mf) {                                                        \
    _Pragma("unroll")                                                                     \
    for (int nf = 0; nf < 3; ++nf)                                                        \
      acc[mf][nf] = __builtin_amdgcn_mfma_f32_16x16x32_bf16(Sa[mf], Sb[nf], acc[mf][nf], 0, 0, 0); \
  }

  // ---- prologue: stage tiles 0,1; wait tile0; issue X=(buf0,k0)
  stage(0, 0);
  stage(1, 64);
  asm volatile("s_waitcnt vmcnt(7)" ::: "memory");
  __builtin_amdgcn_s_barrier();
  __builtin_amdgcn_sched_barrier(0);
  {
    lptr ab = aT + c0;
    lptr bb = bT + c0;
    ISSUE_SET(Xa, Xb, ab, bb)
  }

#pragma unroll 2
  for (int t = 0; t < 32; ++t) {
    const int cur = t & 1;
    lptr aC = aT + cur * 16384;
    lptr bC = bT + cur * 12288;
    // [1] Y <- (cur, k1)
    {
      lptr ab = aC + c1;
      lptr bb = bC + c1;
      ISSUE_SET(Ya, Yb, ab, bb)
    }
    // [2] X ready (Y in flight)
    asm volatile("s_waitcnt lgkmcnt(11)" ::: "memory");
    __builtin_amdgcn_sched_barrier(0);
    __builtin_amdgcn_s_setprio(1);
    MFMA24(Xa, Xb)
    __builtin_amdgcn_s_setprio(0);
    // [3] Y ready
    asm volatile("s_waitcnt lgkmcnt(0)" ::: "memory");
    __builtin_amdgcn_sched_barrier(0);
    __builtin_amdgcn_s_setprio(1);
    MFMA24(Ya, Yb)
    __builtin_amdgcn_s_setprio(0);
    // [4] all waves finished reading cur
    __builtin_amdgcn_s_barrier();
    __builtin_amdgcn_sched_barrier(0);
    // [5] stage t+2 -> cur ; [6] t+1 landed for everyone
    if (t < 30) {
      stage(cur, (t + 2) * 64);
      asm volatile("s_waitcnt vmcnt(7)" ::: "memory");
    } else {
      asm volatile("s_waitcnt vmcnt(0)" ::: "memory");
    }
    __builtin_amdgcn_s_barrier();
    __builtin_amdgcn_sched_barrier(0);
    // [7] X <- (nxt, k0)
    if (t < 31) {
      lptr ab = aT + (cur ^ 1) * 16384 + c0;
      lptr bb = bT + (cur ^ 1) * 12288 + c0;
      ISSUE_SET(Xa, Xb, ab, bb)
    }
  }

  // ---------- epilogue: Q|K -> qk (scaled, biased), V -> transposed vtb
  // gc group base is 16-aligned and segment boundaries (2048,4096) are too -> seg uniform per (wn,ni)
#pragma unroll
  for (int mi = 0; mi < 8; ++mi) {
#pragma unroll
    for (int ni = 0; ni < 3; ++ni) {
      const int gcb = tileN + wn * 48 + ni * 16;
      const int seg = gcb >> 11;                     // 0=Q 1=K 2=V
      const int gc  = gcb + l15;
      const float bvv = ((seg == 0) ? bq : (seg == 1) ? bk : bv)[gc & 2047];
      if (seg < 2) {
        const float scl = (seg == 0) ? qscale : 1.f;
#pragma unroll
        for (int j = 0; j < 4; ++j) {
          const int gr = tileM + wm * 128 + mi * 16 + g * 4 + j;
          qk[(size_t)gr * QSTR + gc] = f2bf((acc[mi][ni][j] + bvv) * scl);
        }
      } else {
        const int dglob = gc - 4096;
        const int hh = dglob >> 7, dd = dglob & 127;
        const int srow0 = tileM + wm * 128 + mi * 16 + g * 4;
        const int bb = srow0 >> 11, ss = srow0 & 2047;
        u16x4 o;
#pragma unroll
        for (int j = 0; j < 4; ++j) o[j] = f2bf(acc[mi][ni][j] + bvv);
        *(u16x4*)(vtb + ((size_t)((bb * NHEADS + hh) * HD + dd)) * SEQ + ss) = o;
      }
    }
  }
#undef ISSUE_SET
#undef MFMA24
}

// ---------------- C = A[M,K] * Bt[N,K]^T + bias (output projection, proven 2-phase) ----------------
__global__ __launch_bounds__(256, 2) void gemm_bt(
    const u16* __restrict__ A, const u16* __restrict__ Bt,
    const float* __restrict__ bias, float* __restrict__ Cout,
    int M, int N, int K)
{
  __shared__ __attribute__((aligned(16))) u16 As[128 * 32];
  __shared__ __attribute__((aligned(16))) u16 Bs[128 * 32];
  const int tid  = threadIdx.x;
  const int lane = tid & 63;
  const int wave = tid >> 6;

  const int nbx   = N >> 7;
  const int nby   = M >> 7;
  const int id    = blockIdx.x;
  const int xcd   = id & 7;
  const int c     = id >> 3;
  const int cpx   = nbx >> 3;
  const int tileN = (xcd * cpx + c / nby) << 7;
  const int tileM = (c % nby) << 7;

  const int g = lane >> 4, r = lane & 15;

  const int srow = lane >> 2;
  const int scol = (lane & 3) * 8;
  const u16* ag0 = A  + (size_t)(tileM + wave * 16 + srow) * K + scol;
  const u16* ag1 = ag0 + (size_t)64 * K;
  const u16* bg0 = Bt + (size_t)(tileN + wave * 16 + srow) * K + scol;
  const u16* bg1 = bg0 + (size_t)64 * K;
  u16* as0 = &As[wave * 512];
  u16* as1 = &As[(wave + 4) * 512];
  u16* bs0 = &Bs[wave * 512];
  u16* bs1 = &Bs[(wave + 4) * 512];

  const int wm = wave >> 1, wn = wave & 1;
  const u16* afp = &As[(wm * 64 + r) * 32 + g * 8];
  const u16* bfp = &Bs[(wn * 64 + r) * 32 + g * 8];

  f32x4 acc[4][4] = {};

  for (int kt = 0; kt < K; kt += 32) {
    __syncthreads();
    gload_lds16(ag0 + kt, as0);
    gload_lds16(ag1 + kt, as1);
    gload_lds16(bg0 + kt, bs0);
    gload_lds16(bg1 + kt, bs1);
    __syncthreads();
    bf16x8 af[4], bf[4];
#pragma unroll
    for (int mi = 0; mi < 4; mi++) af[mi] = ld_frag(afp + mi * 512);
#pragma unroll
    for (int ni = 0; ni < 4; ni++) bf[ni] = ld_frag(bfp + ni * 512);
#pragma unroll
    for (int mi = 0; mi < 4; mi++)
#pragma unroll
      for (int ni = 0; ni < 4; ni++)
        acc[mi][ni] = __builtin_amdgcn_mfma_f32_16x16x32_bf16(af[mi], bf[ni], acc[mi][ni], 0, 0, 0);
  }

#pragma unroll
  for (int mi = 0; mi < 4; mi++) {
#pragma unroll
    for (int ni = 0; ni < 4; ni++) {
      const int gc = tileN + wn * 64 + ni * 16 + r;
      const float bv = bias[gc];
#pragma unroll
      for (int j = 0; j < 4; j++) {
        const int gr = tileM + wm * 64 + mi * 16 + g * 4 + j;
        Cout[(size_t)gr * N + gc] = acc[mi][ni][j] + bv;
      }
    }
  }
}

// ---------------- flash attention: 16x16 MFMA, 32q/wave (2 q-groups), zero-shuffle PV ----------------
__global__ __launch_bounds__(256, 2) void attn_kernel(
    const u16* __restrict__ QKg, const u16* __restrict__ Vtg, u16* __restrict__ Ctx)
{
  __shared__ __attribute__((aligned(16))) u16 Ks[2][32 * 128]; // [kv][16B-unit ^ m(kv)]
  __shared__ __attribute__((aligned(16))) u16 Vs[2][128 * 32]; // [d][kv] linear

  const int tid  = threadIdx.x;
  const int lane = tid & 63;
  const int wave = tid >> 6;
  const int g4   = lane >> 4;
  const int l15  = lane & 15;

  const int wg = ((blockIdx.x & 7) << 6) + (blockIdx.x >> 3);
  const int bh = wg >> 4;                 // 16 blocks per (b,h)
  const int qt = wg & 15;
  const int b  = bh >> 4, h = bh & 15;

  const u16* Qb  = QKg + (size_t)b * SEQ * QSTR + (size_t)h * HD;
  const u16* Kb  = Qb + 2048;
  const u16* Vth = Vtg + (size_t)bh * HD * SEQ;
  u16* Cb = Ctx + (size_t)b * SEQ * HIDDEN + (size_t)h * HD;

  const int qbase = qt * 128 + wave * 32 + l15;

  bf16x8 qf[2][4];
#pragma unroll
  for (int qs = 0; qs < 2; qs++)
#pragma unroll
    for (int dc = 0; dc < 4; dc++)
      qf[qs][dc] = ld_frag(Qb + (size_t)(qbase + qs * 16) * QSTR + dc * 32 + g4 * 8);

  const int kvp0 = (l15 >> 2) * 8 + (l15 & 3);
  const int msw  = (l15 & 3) | (((l15 >> 2) & 1) << 2);

  f32x4 ctx[2][8] = {};
  float m_run[2] = {-1e30f, -1e30f};
  float l_run[2] = {0.f, 0.f};

  auto stage = [&](int buf, int kv0) {
#pragma unroll
    for (int i = 0; i < 2; i++) {
      const int idx = tid + i * 256;
      const int kv = idx >> 4, up = idx & 15;
      const int um = up ^ ((kv & 3) | (((kv >> 3) & 1) << 2));
      gload_lds16(Kb + (size_t)(kv0 + kv) * QSTR + um * 8, &Ks[buf][idx * 8]);
      const int d = idx >> 2, u = idx & 3;
      gload_lds16(Vth + (size_t)d * SEQ + kv0 + u * 8, &Vs[buf][idx * 8]);
    }
  };

  stage(0, 0);
  __syncthreads();

  const int NT = SEQ / 32;
  for (int t = 0; t < NT; t++) {
    const int buf = t & 1;
    if (t + 1 < NT) stage(buf ^ 1, (t + 1) * 32);

    f32x4 s[2][2] = {};
    __builtin_amdgcn_s_setprio(1);
#pragma unroll
    for (int ni = 0; ni < 2; ni++) {
      const int row = kvp0 + ni * 4;
#pragma unroll
      for (int dc = 0; dc < 4; dc++) {
        bf16x8 kf = ld_frag(&Ks[buf][row * 128 + (((dc * 4 + g4) ^ msw) * 8)]);
        s[0][ni] = __builtin_amdgcn_mfma_f32_16x16x32_bf16(kf, qf[0][dc], s[0][ni], 0, 0, 0);
        s[1][ni] = __builtin_amdgcn_mfma_f32_16x16x32_bf16(kf, qf[1][dc], s[1][ni], 0, 0, 0);
      }
    }
    __builtin_amdgcn_s_setprio(0);

    bool ok0, ok1;
    float pmax[2];
#pragma unroll
    for (int qs = 0; qs < 2; qs++) {
      pmax[qs] = fmaxf(fmaxf(fmaxf(s[qs][0][0], s[qs][0][1]), fmaxf(s[qs][0][2], s[qs][0][3])),
                       fmaxf(fmaxf(s[qs][1][0], s[qs][1][1]), fmaxf(s[qs][1][2], s[qs][1][3])));
      pmax[qs] = fmaxf(pmax[qs], __shfl_xor(pmax[qs], 16));
      pmax[qs] = fmaxf(pmax[qs], __shfl_xor(pmax[qs], 32));
    }
    ok0 = (pmax[0] <= m_run[0] + 8.f);
    ok1 = (pmax[1] <= m_run[1] + 8.f);
    if (!__all(ok0 && ok1)) {
#pragma unroll
      for (int qs = 0; qs < 2; qs++) {
        const float mn = fmaxf(m_run[qs], pmax[qs]);
        const float corr = exp2f(m_run[qs] - mn);
        m_run[qs] = mn;
        l_run[qs] *= corr;
#pragma unroll
        for (int dt = 0; dt < 8; dt++)
#pragma unroll
          for (int j = 0; j < 4; j++) ctx[qs][dt][j] *= corr;
      }
    }
    bf16x8 pfrag[2];
#pragma unroll
    for (int qs = 0; qs < 2; qs++) {
      float ps = 0.f;
#pragma unroll
      for (int ni = 0; ni < 2; ni++)
#pragma unroll
        for (int j = 0; j < 4; j++) {
          const float p = exp2f(s[qs][ni][j] - m_run[qs]);
          s[qs][ni][j] = p;
          ps += p;
        }
      ps += __shfl_xor(ps, 16);
      ps += __shfl_xor(ps, 32);
      l_run[qs] += ps;
      u32x4 pw;
      pw[0] = pk2(s[qs][0][0], s[qs][0][1]);
      pw[1] = pk2(s[qs][0][2], s[qs][0][3]);
      pw[2] = pk2(s[qs][1][0], s[qs][1][1]);
      pw[3] = pk2(s[qs][1][2], s[qs][1][3]);
      pfrag[qs] = __builtin_bit_cast(bf16x8, pw);
    }

    __builtin_amdgcn_s_setprio(1);
#pragma unroll
    for (int dt = 0; dt < 8; dt++) {
      bf16x8 vf = ld_frag(&Vs[buf][(dt * 16 + l15) * 32 + g4 * 8]);
      ctx[0][dt] = __builtin_amdgcn_mfma_f32_16x16x32_bf16(vf, pfrag[0], ctx[0][dt], 0, 0, 0);
      ctx[1][dt] = __builtin_amdgcn_mfma_f32_16x16x32_bf16(vf, pfrag[1], ctx[1][dt], 0, 0, 0);
    }
    __builtin_amdgcn_s_setprio(0);

    __syncthreads();
  }

#pragma unroll
  for (int qs = 0; qs < 2; qs++) {
    const float linv = 1.f / l_run[qs];
    u16* crow = Cb + (size_t)(qbase + qs * 16) * HIDDEN;
#pragma unroll
    for (int dt = 0; dt < 8; dt++) {
      u16x4 o;
#pragma unroll
      for (int j = 0; j < 4; j++) o[j] = f2bf(ctx[qs][dt][j] * linv);
      *(u16x4*)&crow[dt * 16 + g4 * 4] = o;
    }
  }
}

// ---------------- launch ----------------
extern "C" void kernel_launch(void* const* d_in, const int* in_sizes, int n_in,
                              void* d_out, int out_size, void* d_ws, size_t ws_size,
                              hipStream_t stream) {
  (void)in_sizes; (void)n_in; (void)out_size; (void)ws_size;
  const float* x  = (const float*)d_in[0];
  const float* wq = (const float*)d_in[1];
  const float* bq = (const float*)d_in[2];
  const float* wk = (const float*)d_in[3];
  const float* bk = (const float*)d_in[4];
  const float* wv = (const float*)d_in[5];
  const float* bv = (const float*)d_in[6];
  const float* wo = (const float*)d_in[7];
  const float* bo = (const float*)d_in[8];

  const size_t NX = (size_t)BATCH * SEQ * HIDDEN;   // 8.39M
  const size_t NW = (size_t)HIDDEN * HIDDEN;        // 4.19M
  u16* xb   = (u16*)d_ws;            // [NX]
  u16* wqb  = xb  + NX;              // [3NW] contiguous Wq|Wk|Wv
  u16* wkb  = wqb + NW;
  u16* wvb  = wkb + NW;
  u16* wob  = wvb + NW;              // [NW]
  u16* qk   = wob + NW;              // [M,4096] fused Q|K
  u16* vtb  = qk  + 2 * NX;          // [B*H, D, S]
  u16* ctxb = xb;                    // x dead after projections

  cvt_kernel<<<2048, 256, 0, stream>>>(x, xb, (int)(NX / 4));
  cvt4_kernel<<<dim3(512, 4), 256, 0, stream>>>(wq, wk, wv, wo, wqb, wkb, wvb, wob, (int)(NW / 4));

  // 1/sqrt(128) * log2(e): scores in log2 units
  const float qscale = 0.12751744174240807f;
  gemm_qkv<<<512, 512, 0, stream>>>(xb, wqb, bq, bk, bv, qk, vtb, qscale);

  attn_kernel<<<512, 256, 0, stream>>>(qk, vtb, ctxb);

  gemm_bt<<<512, 256, 0, stream>>>(ctxb, wob, bo, (float*)d_out, BATCH * SEQ, HIDDEN, HIDDEN);
}

// Round 3
// 289.626 us; speedup vs baseline: 1.1264x; 1.0001x over previous
//
#include <hip/hip_runtime.h>

typedef unsigned short u16;
typedef unsigned int   u32;
typedef float  f32x4   __attribute__((ext_vector_type(4)));
typedef __bf16 bf16x8  __attribute__((ext_vector_type(8)));
typedef u16    u16x8   __attribute__((ext_vector_type(8)));
typedef u16    u16x4   __attribute__((ext_vector_type(4)));
typedef u32    u32x2   __attribute__((ext_vector_type(2)));
typedef u32    u32x4   __attribute__((ext_vector_type(4)));

#define HIDDEN 2048
#define SEQ    2048
#define NHEADS 16
#define HD     128
#define BATCH  2
#define QSTR   4096   // fused Q|K row stride

typedef const __attribute__((address_space(3))) u16* lptr;

__device__ __forceinline__ u16 f2bf(float f) {
  u32 u = __builtin_bit_cast(u32, f);
  u += 0x7FFFu + ((u >> 16) & 1u);          // RNE
  return (u16)(u >> 16);
}
__device__ __forceinline__ u32 pk2(float a, float b) {
  __bf16 x = (__bf16)a, y = (__bf16)b;
  return (u32)__builtin_bit_cast(u16, x) | ((u32)__builtin_bit_cast(u16, y) << 16);
}
__device__ __forceinline__ bf16x8 ld_frag(const u16* p) {
  return __builtin_bit_cast(bf16x8, *(const u32x4*)p);
}
__device__ __forceinline__ void gload_lds16(const u16* g, u16* l) {
  __builtin_amdgcn_global_load_lds((const __attribute__((address_space(1))) u32*)g,
                                   (__attribute__((address_space(3))) u32*)l, 16, 0, 0);
}

// inline-asm LDS read: compiler inserts no auto-waits; we count lgkmcnt manually.
#define DSR(dst, base, lit) \
  asm volatile("ds_read_b128 %0, %1 offset:" lit : "=v"(dst) : "v"(base))

// ---------------- fp32 -> bf16 convert ----------------
__global__ __launch_bounds__(256) void cvt_kernel(const float* __restrict__ src,
                                                  u16* __restrict__ dst, int n4) {
  int stride = gridDim.x * blockDim.x;
  for (int i = blockIdx.x * blockDim.x + threadIdx.x; i < n4; i += stride) {
    f32x4 v = ((const f32x4*)src)[i];
    u16x4 o;
    o[0] = f2bf(v[0]); o[1] = f2bf(v[1]); o[2] = f2bf(v[2]); o[3] = f2bf(v[3]);
    *(u16x4*)(dst + (size_t)i * 4) = o;
  }
}

__global__ __launch_bounds__(256) void cvt4_kernel(
    const float* __restrict__ s0, const float* __restrict__ s1,
    const float* __restrict__ s2, const float* __restrict__ s3,
    u16* __restrict__ o0, u16* __restrict__ o1,
    u16* __restrict__ o2, u16* __restrict__ o3, int n4) {
  const float* src = (blockIdx.y == 0) ? s0 : (blockIdx.y == 1) ? s1 : (blockIdx.y == 2) ? s2 : s3;
  u16* dst = (blockIdx.y == 0) ? o0 : (blockIdx.y == 1) ? o1 : (blockIdx.y == 2) ? o2 : o3;
  int stride = gridDim.x * blockDim.x;
  for (int i = blockIdx.x * blockDim.x + threadIdx.x; i < n4; i += stride) {
    f32x4 v = ((const f32x4*)src)[i];
    u16x4 o;
    o[0] = f2bf(v[0]); o[1] = f2bf(v[1]); o[2] = f2bf(v[2]); o[3] = f2bf(v[3]);
    *(u16x4*)(dst + (size_t)i * 4) = o;
  }
}

// ---------------- fused QKV projection: 256Mx192N tile, BK=64, 8-wave, asm-counted pipeline ----------------
__global__ __launch_bounds__(512, 2) void gemm_qkv(
    const u16* __restrict__ A, const u16* __restrict__ Bt,
    const float* __restrict__ bq, const float* __restrict__ bk,
    const float* __restrict__ bv,
    u16* __restrict__ qk, u16* __restrict__ vtb, float qscale)
{
  __shared__ __attribute__((aligned(16))) u16 As[2][16384];  // 64 KiB
  __shared__ __attribute__((aligned(16))) u16 Bs[2][12288];  // 48 KiB

  const int tid  = threadIdx.x;
  const int lane = tid & 63;
  const int wave = tid >> 6;
  const int l15  = lane & 15;
  const int g    = lane >> 4;
  const int wm   = wave >> 2;            // 0..1 (M half, 128 rows)
  const int wn   = wave & 3;             // 0..3 (N quarter, 48 cols)

  // grid 512 = 8 XCD * (4 Ntiles * 16 Mtiles); bijective, 4 B-panels (3MB) L2-resident per XCD
  const int id  = blockIdx.x;
  const int xcd = id & 7;
  const int c   = id >> 3;               // 0..63
  const int tileN = (xcd * 4 + (c >> 4)) * 192;
  const int tileM = (c & 15) << 8;

  // staging: thread covers row (tid>>3) of each 64-row round, chunk (tid&7)
  const int srow = tid >> 3;
  const int gch8 = ((tid & 7) ^ (srow & 7)) * 8;     // pre-swizzled global chunk
  const u16* agp = A  + (size_t)(tileM + srow) * HIDDEN + gch8;
  const u16* bgp = Bt + (size_t)(tileN + srow) * HIDDEN + gch8;
  u16* asp = (u16*)&As[0][0] + tid * 8;
  u16* bsp = (u16*)&Bs[0][0] + tid * 8;

  auto stage = [&](int buf, int ko) {
    u16* ad = asp + buf * 16384;
    u16* bd = bsp + buf * 12288;
#pragma unroll
    for (int r = 0; r < 4; ++r)
      gload_lds16(agp + (size_t)r * 64 * HIDDEN + ko, ad + r * 4096);
#pragma unroll
    for (int r = 0; r < 3; ++r)
      gload_lds16(bgp + (size_t)r * 64 * HIDDEN + ko, bd + r * 4096);
  };

  // fragment read bases (asm, byte offsets in literals): row stride 16 rows = 2048 B
  const int sw = l15 & 7;
  const int c0 = (g ^ sw) * 8;           // k0 chunk (elements)
  const int c1 = ((g ^ sw) ^ 4) * 8;     // k1 chunk
  lptr aT = (lptr)&As[0][0] + (size_t)(wm * 128 + l15) * 64;
  lptr bT = (lptr)&Bs[0][0] + (size_t)(wn * 48 + l15) * 64;

  f32x4 acc[8][3] = {};
  bf16x8 Xa[8], Xb[3], Ya[8], Yb[3];

#define ISSUE_SET(Sa, Sb, ab, bb)      \
  DSR(Sa[0], ab, "0");                 \
  DSR(Sa[1], ab, "2048");              \
  DSR(Sa[2], ab, "4096");              \
  DSR(Sa[3], ab, "6144");              \
  DSR(Sa[4], ab, "8192");              \
  DSR(Sa[5], ab, "10240");             \
  DSR(Sa[6], ab, "12288");             \
  DSR(Sa[7], ab, "14336");             \
  DSR(Sb[0], bb, "0");                 \
  DSR(Sb[1], bb, "2048");              \
  DSR(Sb[2], bb, "4096");

#define MFMA24(Sa, Sb)                                                                    \
  _Pragma("unroll")                                                                       \
  for (int mf = 0; mf < 8; ++mf) {                                                        \
    _Pragma("unroll")                                                                     \
    for (int nf = 0; nf < 3; ++nf)                                                        \
      acc[mf][nf] = __builtin_amdgcn_mfma_f32_16x16x32_bf16(Sa[mf], Sb[nf], acc[mf][nf], 0, 0, 0); \
  }

  // ---- prologue: stage tiles 0,1; wait tile0; issue X=(buf0,k0)
  stage(0, 0);
  stage(1, 64);
  asm volatile("s_waitcnt vmcnt(7)" ::: "memory");
  __builtin_amdgcn_s_barrier();
  __builtin_amdgcn_sched_barrier(0);
  {
    lptr ab = aT + c0;
    lptr bb = bT + c0;
    ISSUE_SET(Xa, Xb, ab, bb)
  }

#pragma unroll 2
  for (int t = 0; t < 32; ++t) {
    const int cur = t & 1;
    lptr aC = aT + cur * 16384;
    lptr bC = bT + cur * 12288;
    // [1] Y <- (cur, k1)
    {
      lptr ab = aC + c1;
      lptr bb = bC + c1;
      ISSUE_SET(Ya, Yb, ab, bb)
    }
    // [2] X ready (Y in flight)
    asm volatile("s_waitcnt lgkmcnt(11)" ::: "memory");
    __builtin_amdgcn_sched_barrier(0);
    __builtin_amdgcn_s_setprio(1);
    MFMA24(Xa, Xb)
    __builtin_amdgcn_s_setprio(0);
    // [3] Y ready
    asm volatile("s_waitcnt lgkmcnt(0)" ::: "memory");
    __builtin_amdgcn_sched_barrier(0);
    __builtin_amdgcn_s_setprio(1);
    MFMA24(Ya, Yb)
    __builtin_amdgcn_s_setprio(0);
    // [4] all waves finished reading cur
    __builtin_amdgcn_s_barrier();
    __builtin_amdgcn_sched_barrier(0);
    // [5] stage t+2 -> cur ; [6] t+1 landed for everyone
    if (t < 30) {
      stage(cur, (t + 2) * 64);
      asm volatile("s_waitcnt vmcnt(7)" ::: "memory");
    } else {
      asm volatile("s_waitcnt vmcnt(0)" ::: "memory");
    }
    __builtin_amdgcn_s_barrier();
    __builtin_amdgcn_sched_barrier(0);
    // [7] X <- (nxt, k0)
    if (t < 31) {
      lptr ab = aT + (cur ^ 1) * 16384 + c0;
      lptr bb = bT + (cur ^ 1) * 12288 + c0;
      ISSUE_SET(Xa, Xb, ab, bb)
    }
  }

  // ---------- epilogue: Q|K -> qk (scaled, biased), V -> transposed vtb
#pragma unroll
  for (int mi = 0; mi < 8; ++mi) {
#pragma unroll
    for (int ni = 0; ni < 3; ++ni) {
      const int gcb = tileN + wn * 48 + ni * 16;
      const int seg = gcb >> 11;                     // 0=Q 1=K 2=V
      const int gc  = gcb + l15;
      const float bvv = ((seg == 0) ? bq : (seg == 1) ? bk : bv)[gc & 2047];
      if (seg < 2) {
        const float scl = (seg == 0) ? qscale : 1.f;
#pragma unroll
        for (int j = 0; j < 4; ++j) {
          const int gr = tileM + wm * 128 + mi * 16 + g * 4 + j;
          qk[(size_t)gr * QSTR + gc] = f2bf((acc[mi][ni][j] + bvv) * scl);
        }
      } else {
        const int dglob = gc - 4096;
        const int hh = dglob >> 7, dd = dglob & 127;
        const int srow0 = tileM + wm * 128 + mi * 16 + g * 4;
        const int bb = srow0 >> 11, ss = srow0 & 2047;
        u16x4 o;
#pragma unroll
        for (int j = 0; j < 4; ++j) o[j] = f2bf(acc[mi][ni][j] + bvv);
        *(u16x4*)(vtb + ((size_t)((bb * NHEADS + hh) * HD + dd)) * SEQ + ss) = o;
      }
    }
  }
#undef ISSUE_SET
#undef MFMA24
}

// ---------------- C = A[M,K] * Bt[N,K]^T + bias (output projection, proven 2-phase) ----------------
__global__ __launch_bounds__(256, 2) void gemm_bt(
    const u16* __restrict__ A, const u16* __restrict__ Bt,
    const float* __restrict__ bias, float* __restrict__ Cout,
    int M, int N, int K)
{
  __shared__ __attribute__((aligned(16))) u16 As[128 * 32];
  __shared__ __attribute__((aligned(16))) u16 Bs[128 * 32];
  const int tid  = threadIdx.x;
  const int lane = tid & 63;
  const int wave = tid >> 6;

  const int nbx   = N >> 7;
  const int nby   = M >> 7;
  const int id    = blockIdx.x;
  const int xcd   = id & 7;
  const int c     = id >> 3;
  const int cpx   = nbx >> 3;
  const int tileN = (xcd * cpx + c / nby) << 7;
  const int tileM = (c % nby) << 7;

  const int g = lane >> 4, r = lane & 15;

  const int srow = lane >> 2;
  const int scol = (lane & 3) * 8;
  const u16* ag0 = A  + (size_t)(tileM + wave * 16 + srow) * K + scol;
  const u16* ag1 = ag0 + (size_t)64 * K;
  const u16* bg0 = Bt + (size_t)(tileN + wave * 16 + srow) * K + scol;
  const u16* bg1 = bg0 + (size_t)64 * K;
  u16* as0 = &As[wave * 512];
  u16* as1 = &As[(wave + 4) * 512];
  u16* bs0 = &Bs[wave * 512];
  u16* bs1 = &Bs[(wave + 4) * 512];

  const int wm = wave >> 1, wn = wave & 1;
  const u16* afp = &As[(wm * 64 + r) * 32 + g * 8];
  const u16* bfp = &Bs[(wn * 64 + r) * 32 + g * 8];

  f32x4 acc[4][4] = {};

  for (int kt = 0; kt < K; kt += 32) {
    __syncthreads();
    gload_lds16(ag0 + kt, as0);
    gload_lds16(ag1 + kt, as1);
    gload_lds16(bg0 + kt, bs0);
    gload_lds16(bg1 + kt, bs1);
    __syncthreads();
    bf16x8 af[4], bf[4];
#pragma unroll
    for (int mi = 0; mi < 4; mi++) af[mi] = ld_frag(afp + mi * 512);
#pragma unroll
    for (int ni = 0; ni < 4; ni++) bf[ni] = ld_frag(bfp + ni * 512);
#pragma unroll
    for (int mi = 0; mi < 4; mi++)
#pragma unroll
      for (int ni = 0; ni < 4; ni++)
        acc[mi][ni] = __builtin_amdgcn_mfma_f32_16x16x32_bf16(af[mi], bf[ni], acc[mi][ni], 0, 0, 0);
  }

#pragma unroll
  for (int mi = 0; mi < 4; mi++) {
#pragma unroll
    for (int ni = 0; ni < 4; ni++) {
      const int gc = tileN + wn * 64 + ni * 16 + r;
      const float bv = bias[gc];
#pragma unroll
      for (int j = 0; j < 4; j++) {
        const int gr = tileM + wm * 64 + mi * 16 + g * 4 + j;
        Cout[(size_t)gr * N + gc] = acc[mi][ni][j] + bv;
      }
    }
  }
}

// ---------------- flash attention: 16 q/wave, 64-row blocks, grid 1024 (4 blocks/CU) ----------------
// Occupancy 2x vs 32q/wave; V LDS chunk-swizzled (source-side) -> 2-way banks (free).
__global__ __launch_bounds__(256, 4) void attn_kernel(
    const u16* __restrict__ QKg, const u16* __restrict__ Vtg, u16* __restrict__ Ctx)
{
  __shared__ __attribute__((aligned(16))) u16 Ks[2][32 * 128]; // [kv][16B-unit ^ m(kv)]
  __shared__ __attribute__((aligned(16))) u16 Vs[2][128 * 32]; // [d][kv-chunk ^ ((d>>2)&3)]

  const int tid  = threadIdx.x;
  const int lane = tid & 63;
  const int wave = tid >> 6;
  const int g4   = lane >> 4;
  const int l15  = lane & 15;

  // XCD-chunked bijective swizzle over 1024 blocks: 128 per XCD, 32 q-tiles per (b,h)
  const int wg = ((blockIdx.x & 7) << 7) + (blockIdx.x >> 3);
  const int bh = wg >> 5;                 // 32 blocks per (b,h)
  const int qt = wg & 31;
  const int b  = bh >> 4, h = bh & 15;

  const u16* Qb  = QKg + (size_t)b * SEQ * QSTR + (size_t)h * HD;
  const u16* Kb  = Qb + 2048;
  const u16* Vth = Vtg + (size_t)bh * HD * SEQ;
  u16* Cb = Ctx + (size_t)b * SEQ * HIDDEN + (size_t)h * HD;

  const int qbase = qt * 64 + wave * 16 + l15;

  // Q fragments (B-operand): Q[q][dc*32 + g4*8 + e]
  bf16x8 qf[4];
#pragma unroll
  for (int dc = 0; dc < 4; dc++)
    qf[dc] = ld_frag(Qb + (size_t)qbase * QSTR + dc * 32 + g4 * 8);

  // K A-frag addressing: rows kv' and swizzle key (same for ni=0,1)
  const int kvp0 = (l15 >> 2) * 8 + (l15 & 3);
  const int msw  = (l15 & 3) | (((l15 >> 2) & 1) << 2);
  const int vch  = (g4 ^ (l15 >> 2)) * 8;   // V read chunk (2-way banks)

  f32x4 ctx[8] = {};
  float m_run = -1e30f;
  float l_run = 0.f;

  auto stage = [&](int buf, int kv0) {
#pragma unroll
    for (int i = 0; i < 2; i++) {
      const int idx = tid + i * 256;
      const int kv = idx >> 4, up = idx & 15;
      const int um = up ^ ((kv & 3) | (((kv >> 3) & 1) << 2));
      gload_lds16(Kb + (size_t)(kv0 + kv) * QSTR + um * 8, &Ks[buf][idx * 8]);
      const int d = idx >> 2, u = idx & 3;
      const int uv = u ^ ((d >> 2) & 3);          // source-side V swizzle
      gload_lds16(Vth + (size_t)d * SEQ + kv0 + uv * 8, &Vs[buf][idx * 8]);
    }
  };

  stage(0, 0);
  __syncthreads();

  const int NT = SEQ / 32;
  for (int t = 0; t < NT; t++) {
    const int buf = t & 1;
    if (t + 1 < NT) stage(buf ^ 1, (t + 1) * 32);

    // S^T: 2 kv-blocks x 4 d-chunks
    f32x4 s[2] = {};
    __builtin_amdgcn_s_setprio(1);
#pragma unroll
    for (int ni = 0; ni < 2; ni++) {
      const int row = kvp0 + ni * 4;
#pragma unroll
      for (int dc = 0; dc < 4; dc++) {
        bf16x8 kf = ld_frag(&Ks[buf][row * 128 + (((dc * 4 + g4) ^ msw) * 8)]);
        s[ni] = __builtin_amdgcn_mfma_f32_16x16x32_bf16(kf, qf[dc], s[ni], 0, 0, 0);
      }
    }
    __builtin_amdgcn_s_setprio(0);

    // online softmax (log2 units); lane owns q, 8 scores kv = g4*8 + ni*4 + j
    float pmax = fmaxf(fmaxf(fmaxf(s[0][0], s[0][1]), fmaxf(s[0][2], s[0][3])),
                       fmaxf(fmaxf(s[1][0], s[1][1]), fmaxf(s[1][2], s[1][3])));
    pmax = fmaxf(pmax, __shfl_xor(pmax, 16));
    pmax = fmaxf(pmax, __shfl_xor(pmax, 32));
    if (!__all(pmax <= m_run + 8.f)) {            // defer-max (T13)
      const float mn = fmaxf(m_run, pmax);
      const float corr = exp2f(m_run - mn);
      m_run = mn;
      l_run *= corr;
#pragma unroll
      for (int dt = 0; dt < 8; dt++)
#pragma unroll
        for (int j = 0; j < 4; j++) ctx[dt][j] *= corr;
    }
    float ps = 0.f;
#pragma unroll
    for (int ni = 0; ni < 2; ni++)
#pragma unroll
      for (int j = 0; j < 4; j++) {
        const float p = exp2f(s[ni][j] - m_run);
        s[ni][j] = p;
        ps += p;
      }
    ps += __shfl_xor(ps, 16);
    ps += __shfl_xor(ps, 32);
    l_run += ps;
    u32x4 pw;
    pw[0] = pk2(s[0][0], s[0][1]);
    pw[1] = pk2(s[0][2], s[0][3]);
    pw[2] = pk2(s[1][0], s[1][1]);
    pw[3] = pk2(s[1][2], s[1][3]);
    const bf16x8 pfrag = __builtin_bit_cast(bf16x8, pw);

    // PV: ctx^T[d][q] += V^T[d][kv] * P[kv][q]
    __builtin_amdgcn_s_setprio(1);
#pragma unroll
    for (int dt = 0; dt < 8; dt++) {
      bf16x8 vf = ld_frag(&Vs[buf][(dt * 16 + l15) * 32 + vch]);
      ctx[dt] = __builtin_amdgcn_mfma_f32_16x16x32_bf16(vf, pfrag, ctx[dt], 0, 0, 0);
    }
    __builtin_amdgcn_s_setprio(0);

    __syncthreads();   // drains staging vmcnt + buffer handoff
  }

  // epilogue: d = dt*16 + g4*4 + j
  const float linv = 1.f / l_run;
  u16* crow = Cb + (size_t)qbase * HIDDEN;
#pragma unroll
  for (int dt = 0; dt < 8; dt++) {
    u16x4 o;
#pragma unroll
    for (int j = 0; j < 4; j++) o[j] = f2bf(ctx[dt][j] * linv);
    *(u16x4*)&crow[dt * 16 + g4 * 4] = o;
  }
}

// ---------------- launch ----------------
extern "C" void kernel_launch(void* const* d_in, const int* in_sizes, int n_in,
                              void* d_out, int out_size, void* d_ws, size_t ws_size,
                              hipStream_t stream) {
  (void)in_sizes; (void)n_in; (void)out_size; (void)ws_size;
  const float* x  = (const float*)d_in[0];
  const float* wq = (const float*)d_in[1];
  const float* bq = (const float*)d_in[2];
  const float* wk = (const float*)d_in[3];
  const float* bk = (const float*)d_in[4];
  const float* wv = (const float*)d_in[5];
  const float* bv = (const float*)d_in[6];
  const float* wo = (const float*)d_in[7];
  const float* bo = (const float*)d_in[8];

  const size_t NX = (size_t)BATCH * SEQ * HIDDEN;   // 8.39M
  const size_t NW = (size_t)HIDDEN * HIDDEN;        // 4.19M
  u16* xb   = (u16*)d_ws;            // [NX]
  u16* wqb  = xb  + NX;              // [3NW] contiguous Wq|Wk|Wv
  u16* wkb  = wqb + NW;
  u16* wvb  = wkb + NW;
  u16* wob  = wvb + NW;              // [NW]
  u16* qk   = wob + NW;              // [M,4096] fused Q|K
  u16* vtb  = qk  + 2 * NX;          // [B*H, D, S]
  u16* ctxb = xb;                    // x dead after projections

  cvt_kernel<<<2048, 256, 0, stream>>>(x, xb, (int)(NX / 4));
  cvt4_kernel<<<dim3(512, 4), 256, 0, stream>>>(wq, wk, wv, wo, wqb, wkb, wvb, wob, (int)(NW / 4));

  // 1/sqrt(128) * log2(e): scores in log2 units
  const float qscale = 0.12751744174240807f;
  gemm_qkv<<<512, 512, 0, stream>>>(xb, wqb, bq, bk, bv, qk, vtb, qscale);

  attn_kernel<<<1024, 256, 0, stream>>>(qk, vtb, ctxb);

  gemm_bt<<<512, 256, 0, stream>>>(ctxb, wob, bo, (float*)d_out, BATCH * SEQ, HIDDEN, HIDDEN);
}

// Round 4
// 287.934 us; speedup vs baseline: 1.1330x; 1.0059x over previous
//
#include <hip/hip_runtime.h>

typedef unsigned short u16;
typedef unsigned int   u32;
typedef float  f32x4   __attribute__((ext_vector_type(4)));
typedef __bf16 bf16x8  __attribute__((ext_vector_type(8)));
typedef u16    u16x8   __attribute__((ext_vector_type(8)));
typedef u16    u16x4   __attribute__((ext_vector_type(4)));
typedef u32    u32x2   __attribute__((ext_vector_type(2)));
typedef u32    u32x4   __attribute__((ext_vector_type(4)));

#define HIDDEN 2048
#define SEQ    2048
#define NHEADS 16
#define HD     128
#define BATCH  2
#define QSTR   4096   // fused Q|K row stride

typedef const __attribute__((address_space(3))) u16* lptr;

__device__ __forceinline__ u16 f2bf(float f) {
  u32 u = __builtin_bit_cast(u32, f);
  u += 0x7FFFu + ((u >> 16) & 1u);          // RNE
  return (u16)(u >> 16);
}
__device__ __forceinline__ u32 pk2(float a, float b) {
  __bf16 x = (__bf16)a, y = (__bf16)b;
  return (u32)__builtin_bit_cast(u16, x) | ((u32)__builtin_bit_cast(u16, y) << 16);
}
__device__ __forceinline__ bf16x8 ld_frag(const u16* p) {
  return __builtin_bit_cast(bf16x8, *(const u32x4*)p);
}
__device__ __forceinline__ void gload_lds16(const u16* g, u16* l) {
  __builtin_amdgcn_global_load_lds((const __attribute__((address_space(1))) u32*)g,
                                   (__attribute__((address_space(3))) u32*)l, 16, 0, 0);
}

// inline-asm LDS read: compiler inserts no auto-waits; we count lgkmcnt manually.
#define DSR(dst, base, lit) \
  asm volatile("ds_read_b128 %0, %1 offset:" lit : "=v"(dst) : "v"(base))

#define MFMA16(d, a, b) d = __builtin_amdgcn_mfma_f32_16x16x32_bf16(a, b, d, 0, 0, 0)

// ---------------- fp32 -> bf16 convert ----------------
__global__ __launch_bounds__(256) void cvt_kernel(const float* __restrict__ src,
                                                  u16* __restrict__ dst, int n4) {
  int stride = gridDim.x * blockDim.x;
  for (int i = blockIdx.x * blockDim.x + threadIdx.x; i < n4; i += stride) {
    f32x4 v = ((const f32x4*)src)[i];
    u16x4 o;
    o[0] = f2bf(v[0]); o[1] = f2bf(v[1]); o[2] = f2bf(v[2]); o[3] = f2bf(v[3]);
    *(u16x4*)(dst + (size_t)i * 4) = o;
  }
}

__global__ __launch_bounds__(256) void cvt4_kernel(
    const float* __restrict__ s0, const float* __restrict__ s1,
    const float* __restrict__ s2, const float* __restrict__ s3,
    u16* __restrict__ o0, u16* __restrict__ o1,
    u16* __restrict__ o2, u16* __restrict__ o3, int n4) {
  const float* src = (blockIdx.y == 0) ? s0 : (blockIdx.y == 1) ? s1 : (blockIdx.y == 2) ? s2 : s3;
  u16* dst = (blockIdx.y == 0) ? o0 : (blockIdx.y == 1) ? o1 : (blockIdx.y == 2) ? o2 : o3;
  int stride = gridDim.x * blockDim.x;
  for (int i = blockIdx.x * blockDim.x + threadIdx.x; i < n4; i += stride) {
    f32x4 v = ((const f32x4*)src)[i];
    u16x4 o;
    o[0] = f2bf(v[0]); o[1] = f2bf(v[1]); o[2] = f2bf(v[2]); o[3] = f2bf(v[3]);
    *(u16x4*)(dst + (size_t)i * 4) = o;
  }
}

// ---------------- fused QKV projection: 256Mx192N tile, BK=64, 8-wave, asm-counted pipeline ----------------
__global__ __launch_bounds__(512, 2) void gemm_qkv(
    const u16* __restrict__ A, const u16* __restrict__ Bt,
    const float* __restrict__ bq, const float* __restrict__ bk,
    const float* __restrict__ bv,
    u16* __restrict__ qk, u16* __restrict__ vtb, float qscale)
{
  __shared__ __attribute__((aligned(16))) u16 As[2][16384];  // 64 KiB
  __shared__ __attribute__((aligned(16))) u16 Bs[2][12288];  // 48 KiB

  const int tid  = threadIdx.x;
  const int lane = tid & 63;
  const int wave = tid >> 6;
  const int l15  = lane & 15;
  const int g    = lane >> 4;
  const int wm   = wave >> 2;            // 0..1 (M half, 128 rows)
  const int wn   = wave & 3;             // 0..3 (N quarter, 48 cols)

  // grid 512 = 8 XCD * (4 Ntiles * 16 Mtiles); bijective, 4 B-panels (3MB) L2-resident per XCD
  const int id  = blockIdx.x;
  const int xcd = id & 7;
  const int c   = id >> 3;               // 0..63
  const int tileN = (xcd * 4 + (c >> 4)) * 192;
  const int tileM = (c & 15) << 8;

  // staging: thread covers row (tid>>3) of each 64-row round, chunk (tid&7)
  const int srow = tid >> 3;
  const int gch8 = ((tid & 7) ^ (srow & 7)) * 8;     // pre-swizzled global chunk
  const u16* agp = A  + (size_t)(tileM + srow) * HIDDEN + gch8;
  const u16* bgp = Bt + (size_t)(tileN + srow) * HIDDEN + gch8;
  u16* asp = (u16*)&As[0][0] + tid * 8;
  u16* bsp = (u16*)&Bs[0][0] + tid * 8;

  auto stage = [&](int buf, int ko) {
    u16* ad = asp + buf * 16384;
    u16* bd = bsp + buf * 12288;
#pragma unroll
    for (int r = 0; r < 4; ++r)
      gload_lds16(agp + (size_t)r * 64 * HIDDEN + ko, ad + r * 4096);
#pragma unroll
    for (int r = 0; r < 3; ++r)
      gload_lds16(bgp + (size_t)r * 64 * HIDDEN + ko, bd + r * 4096);
  };

  // fragment read bases (asm, byte offsets in literals): row stride 16 rows = 2048 B
  const int sw = l15 & 7;
  const int c0 = (g ^ sw) * 8;           // k0 chunk (elements)
  const int c1 = ((g ^ sw) ^ 4) * 8;     // k1 chunk
  lptr aT = (lptr)&As[0][0] + (size_t)(wm * 128 + l15) * 64;
  lptr bT = (lptr)&Bs[0][0] + (size_t)(wn * 48 + l15) * 64;

  f32x4 acc[8][3] = {};
  bf16x8 Xa[8], Xb[3], Ya[8], Yb[3];

#define ISSUE_SET(Sa, Sb, ab, bb)      \
  DSR(Sa[0], ab, "0");                 \
  DSR(Sa[1], ab, "2048");              \
  DSR(Sa[2], ab, "4096");              \
  DSR(Sa[3], ab, "6144");              \
  DSR(Sa[4], ab, "8192");              \
  DSR(Sa[5], ab, "10240");             \
  DSR(Sa[6], ab, "12288");             \
  DSR(Sa[7], ab, "14336");             \
  DSR(Sb[0], bb, "0");                 \
  DSR(Sb[1], bb, "2048");              \
  DSR(Sb[2], bb, "4096");

#define MFMA24(Sa, Sb)                                                                    \
  _Pragma("unroll")                                                                       \
  for (int mf = 0; mf < 8; ++mf) {                                                        \
    _Pragma("unroll")                                                                     \
    for (int nf = 0; nf < 3; ++nf)                                                        \
      acc[mf][nf] = __builtin_amdgcn_mfma_f32_16x16x32_bf16(Sa[mf], Sb[nf], acc[mf][nf], 0, 0, 0); \
  }

  // ---- prologue: stage tiles 0,1; wait tile0; issue X=(buf0,k0)
  stage(0, 0);
  stage(1, 64);
  asm volatile("s_waitcnt vmcnt(7)" ::: "memory");
  __builtin_amdgcn_s_barrier();
  __builtin_amdgcn_sched_barrier(0);
  {
    lptr ab = aT + c0;
    lptr bb = bT + c0;
    ISSUE_SET(Xa, Xb, ab, bb)
  }

#pragma unroll 2
  for (int t = 0; t < 32; ++t) {
    const int cur = t & 1;
    lptr aC = aT + cur * 16384;
    lptr bC = bT + cur * 12288;
    // [1] Y <- (cur, k1)
    {
      lptr ab = aC + c1;
      lptr bb = bC + c1;
      ISSUE_SET(Ya, Yb, ab, bb)
    }
    // [2] X ready (Y in flight)
    asm volatile("s_waitcnt lgkmcnt(11)" ::: "memory");
    __builtin_amdgcn_sched_barrier(0);
    __builtin_amdgcn_s_setprio(1);
    MFMA24(Xa, Xb)
    __builtin_amdgcn_s_setprio(0);
    // [3] Y ready
    asm volatile("s_waitcnt lgkmcnt(0)" ::: "memory");
    __builtin_amdgcn_sched_barrier(0);
    __builtin_amdgcn_s_setprio(1);
    MFMA24(Ya, Yb)
    __builtin_amdgcn_s_setprio(0);
    // [4] all waves finished reading cur
    __builtin_amdgcn_s_barrier();
    __builtin_amdgcn_sched_barrier(0);
    // [5] stage t+2 -> cur ; [6] t+1 landed for everyone
    if (t < 30) {
      stage(cur, (t + 2) * 64);
      asm volatile("s_waitcnt vmcnt(7)" ::: "memory");
    } else {
      asm volatile("s_waitcnt vmcnt(0)" ::: "memory");
    }
    __builtin_amdgcn_s_barrier();
    __builtin_amdgcn_sched_barrier(0);
    // [7] X <- (nxt, k0)
    if (t < 31) {
      lptr ab = aT + (cur ^ 1) * 16384 + c0;
      lptr bb = bT + (cur ^ 1) * 12288 + c0;
      ISSUE_SET(Xa, Xb, ab, bb)
    }
  }

  // ---------- epilogue: Q|K -> qk (scaled, biased), V -> transposed vtb
#pragma unroll
  for (int mi = 0; mi < 8; ++mi) {
#pragma unroll
    for (int ni = 0; ni < 3; ++ni) {
      const int gcb = tileN + wn * 48 + ni * 16;
      const int seg = gcb >> 11;                     // 0=Q 1=K 2=V
      const int gc  = gcb + l15;
      const float bvv = ((seg == 0) ? bq : (seg == 1) ? bk : bv)[gc & 2047];
      if (seg < 2) {
        const float scl = (seg == 0) ? qscale : 1.f;
#pragma unroll
        for (int j = 0; j < 4; ++j) {
          const int gr = tileM + wm * 128 + mi * 16 + g * 4 + j;
          qk[(size_t)gr * QSTR + gc] = f2bf((acc[mi][ni][j] + bvv) * scl);
        }
      } else {
        const int dglob = gc - 4096;
        const int hh = dglob >> 7, dd = dglob & 127;
        const int srow0 = tileM + wm * 128 + mi * 16 + g * 4;
        const int bb = srow0 >> 11, ss = srow0 & 2047;
        u16x4 o;
#pragma unroll
        for (int j = 0; j < 4; ++j) o[j] = f2bf(acc[mi][ni][j] + bvv);
        *(u16x4*)(vtb + ((size_t)((bb * NHEADS + hh) * HD + dd)) * SEQ + ss) = o;
      }
    }
  }
#undef ISSUE_SET
#undef MFMA24
}

// ---------------- C = A[M,K] * Bt[N,K]^T + bias (output projection, proven 2-phase) ----------------
__global__ __launch_bounds__(256, 2) void gemm_bt(
    const u16* __restrict__ A, const u16* __restrict__ Bt,
    const float* __restrict__ bias, float* __restrict__ Cout,
    int M, int N, int K)
{
  __shared__ __attribute__((aligned(16))) u16 As[128 * 32];
  __shared__ __attribute__((aligned(16))) u16 Bs[128 * 32];
  const int tid  = threadIdx.x;
  const int lane = tid & 63;
  const int wave = tid >> 6;

  const int nbx   = N >> 7;
  const int nby   = M >> 7;
  const int id    = blockIdx.x;
  const int xcd   = id & 7;
  const int c     = id >> 3;
  const int cpx   = nbx >> 3;
  const int tileN = (xcd * cpx + c / nby) << 7;
  const int tileM = (c % nby) << 7;

  const int g = lane >> 4, r = lane & 15;

  const int srow = lane >> 2;
  const int scol = (lane & 3) * 8;
  const u16* ag0 = A  + (size_t)(tileM + wave * 16 + srow) * K + scol;
  const u16* ag1 = ag0 + (size_t)64 * K;
  const u16* bg0 = Bt + (size_t)(tileN + wave * 16 + srow) * K + scol;
  const u16* bg1 = bg0 + (size_t)64 * K;
  u16* as0 = &As[wave * 512];
  u16* as1 = &As[(wave + 4) * 512];
  u16* bs0 = &Bs[wave * 512];
  u16* bs1 = &Bs[(wave + 4) * 512];

  const int wm = wave >> 1, wn = wave & 1;
  const u16* afp = &As[(wm * 64 + r) * 32 + g * 8];
  const u16* bfp = &Bs[(wn * 64 + r) * 32 + g * 8];

  f32x4 acc[4][4] = {};

  for (int kt = 0; kt < K; kt += 32) {
    __syncthreads();
    gload_lds16(ag0 + kt, as0);
    gload_lds16(ag1 + kt, as1);
    gload_lds16(bg0 + kt, bs0);
    gload_lds16(bg1 + kt, bs1);
    __syncthreads();
    bf16x8 af[4], bf[4];
#pragma unroll
    for (int mi = 0; mi < 4; mi++) af[mi] = ld_frag(afp + mi * 512);
#pragma unroll
    for (int ni = 0; ni < 4; ni++) bf[ni] = ld_frag(bfp + ni * 512);
#pragma unroll
    for (int mi = 0; mi < 4; mi++)
#pragma unroll
      for (int ni = 0; ni < 4; ni++)
        acc[mi][ni] = __builtin_amdgcn_mfma_f32_16x16x32_bf16(af[mi], bf[ni], acc[mi][ni], 0, 0, 0);
  }

#pragma unroll
  for (int mi = 0; mi < 4; mi++) {
#pragma unroll
    for (int ni = 0; ni < 4; ni++) {
      const int gc = tileN + wn * 64 + ni * 16 + r;
      const float bv = bias[gc];
#pragma unroll
      for (int j = 0; j < 4; j++) {
        const int gr = tileM + wm * 64 + mi * 16 + g * 4 + j;
        Cout[(size_t)gr * N + gc] = acc[mi][ni][j] + bv;
      }
    }
  }
}

// ---------------- flash attention: 16 q/wave, asm-counted LDS pipeline ----------------
// [A] stage(t+1) ; vmcnt(4) ; barrier    (next tile's 4 loads stay in flight)
// [C] 8 asm ds_read K-frags ; lgkm(4) -> 4 QK MFMA ; lgkm(0) -> 4 QK MFMA
// [D] online softmax (log2 units, defer-max)
// [E] 8 asm ds_read V-frags ; lgkm(4) -> 4 PV MFMA ; lgkm(0) -> 4 PV MFMA
// [F] barrier (all reads of buf retired -> next stage may overwrite)
__global__ __launch_bounds__(256, 3) void attn_kernel(
    const u16* __restrict__ QKg, const u16* __restrict__ Vtg, u16* __restrict__ Ctx)
{
  __shared__ __attribute__((aligned(16))) u16 Ks[2][32 * 128]; // [kv][16B-unit ^ m(kv)]
  __shared__ __attribute__((aligned(16))) u16 Vs[2][128 * 32]; // [d][kv-chunk ^ ((d>>2)&3)]

  const int tid  = threadIdx.x;
  const int lane = tid & 63;
  const int wave = tid >> 6;
  const int g4   = lane >> 4;
  const int l15  = lane & 15;

  // XCD-chunked bijective swizzle over 1024 blocks: 128 per XCD, 32 q-tiles per (b,h)
  const int wg = ((blockIdx.x & 7) << 7) + (blockIdx.x >> 3);
  const int bh = wg >> 5;                 // 32 blocks per (b,h)
  const int qt = wg & 31;
  const int b  = bh >> 4, h = bh & 15;

  const u16* Qb  = QKg + (size_t)b * SEQ * QSTR + (size_t)h * HD;
  const u16* Kb  = Qb + 2048;
  const u16* Vth = Vtg + (size_t)bh * HD * SEQ;
  u16* Cb = Ctx + (size_t)b * SEQ * HIDDEN + (size_t)h * HD;

  const int qbase = qt * 64 + wave * 16 + l15;

  // Q fragments (B-operand): Q[q][dc*32 + g4*8 + e]
  bf16x8 qf[4];
#pragma unroll
  for (int dc = 0; dc < 4; dc++)
    qf[dc] = ld_frag(Qb + (size_t)qbase * QSTR + dc * 32 + g4 * 8);

  // K A-frag addressing: rows kv' = kvp0 + ni*4, swizzled 16B-unit (dc*4+g4)^msw
  const int kvp0 = (l15 >> 2) * 8 + (l15 & 3);
  const int msw  = (l15 & 3) | (((l15 >> 2) & 1) << 2);

  lptr kB = (lptr)&Ks[0][0] + kvp0 * 128;
  lptr kb0 = kB + (((0 * 4 + g4) ^ msw) * 8);
  lptr kb1 = kB + (((1 * 4 + g4) ^ msw) * 8);
  lptr kb2 = kB + (((2 * 4 + g4) ^ msw) * 8);
  lptr kb3 = kB + (((3 * 4 + g4) ^ msw) * 8);
  lptr vb0 = (lptr)&Vs[0][0] + l15 * 32 + ((g4 ^ (l15 >> 2)) * 8);

  f32x4 ctx[8] = {};
  float m_run = -1e30f;
  float l_run = 0.f;

  auto stage = [&](int buf, int kv0) {
#pragma unroll
    for (int i = 0; i < 2; i++) {
      const int idx = tid + i * 256;
      const int kv = idx >> 4, up = idx & 15;
      const int um = up ^ ((kv & 3) | (((kv >> 3) & 1) << 2));
      gload_lds16(Kb + (size_t)(kv0 + kv) * QSTR + um * 8, &Ks[buf][idx * 8]);
      const int d = idx >> 2, u = idx & 3;
      const int uv = u ^ ((d >> 2) & 3);          // source-side V swizzle
      gload_lds16(Vth + (size_t)d * SEQ + kv0 + uv * 8, &Vs[buf][idx * 8]);
    }
  };

  stage(0, 0);

  const int NT = SEQ / 32;
  for (int t = 0; t < NT; t++) {
    const int buf = t & 1;

    // [A] prefetch next tile; counted wait: own stage(t) landed, stage(t+1) in flight
    if (t + 1 < NT) {
      stage(buf ^ 1, (t + 1) * 32);
      asm volatile("s_waitcnt vmcnt(4)" ::: "memory");
    } else {
      asm volatile("s_waitcnt vmcnt(0)" ::: "memory");
    }
    __builtin_amdgcn_s_barrier();
    __builtin_amdgcn_sched_barrier(0);

    // [C] QK^T: batched asm reads, counted lgkm
    bf16x8 k0, k1, k2, k3, k4, k5, k6, k7;
    {
      const int bo = buf * 4096;   // Ks buf stride (elements)
      lptr a0 = kb0 + bo, a1 = kb1 + bo, a2 = kb2 + bo, a3 = kb3 + bo;
      DSR(k0, a0, "0");
      DSR(k1, a1, "0");
      DSR(k2, a2, "0");
      DSR(k3, a3, "0");
      DSR(k4, a0, "1024");
      DSR(k5, a1, "1024");
      DSR(k6, a2, "1024");
      DSR(k7, a3, "1024");
    }
    f32x4 s0 = {}, s1 = {};
    asm volatile("s_waitcnt lgkmcnt(4)" ::: "memory");
    __builtin_amdgcn_sched_barrier(0);
    __builtin_amdgcn_s_setprio(1);
    MFMA16(s0, k0, qf[0]); MFMA16(s0, k1, qf[1]);
    MFMA16(s0, k2, qf[2]); MFMA16(s0, k3, qf[3]);
    __builtin_amdgcn_sched_barrier(0);
    asm volatile("s_waitcnt lgkmcnt(0)" ::: "memory");
    __builtin_amdgcn_sched_barrier(0);
    MFMA16(s1, k4, qf[0]); MFMA16(s1, k5, qf[1]);
    MFMA16(s1, k6, qf[2]); MFMA16(s1, k7, qf[3]);
    __builtin_amdgcn_s_setprio(0);
    __builtin_amdgcn_sched_barrier(0);

    // [D] online softmax (log2 units); lane owns q, 8 scores kv = g4*8 + ni*4 + j
    float pmax = fmaxf(fmaxf(fmaxf(s0[0], s0[1]), fmaxf(s0[2], s0[3])),
                       fmaxf(fmaxf(s1[0], s1[1]), fmaxf(s1[2], s1[3])));
    pmax = fmaxf(pmax, __shfl_xor(pmax, 16));
    pmax = fmaxf(pmax, __shfl_xor(pmax, 32));
    if (!__all(pmax <= m_run + 8.f)) {            // defer-max (T13)
      const float mn = fmaxf(m_run, pmax);
      const float corr = exp2f(m_run - mn);
      m_run = mn;
      l_run *= corr;
#pragma unroll
      for (int dt = 0; dt < 8; dt++)
#pragma unroll
        for (int j = 0; j < 4; j++) ctx[dt][j] *= corr;
    }
    float ps = 0.f;
#pragma unroll
    for (int j = 0; j < 4; j++) {
      s0[j] = exp2f(s0[j] - m_run);
      s1[j] = exp2f(s1[j] - m_run);
      ps += s0[j] + s1[j];
    }
    ps += __shfl_xor(ps, 16);
    ps += __shfl_xor(ps, 32);
    l_run += ps;
    u32x4 pw;
    pw[0] = pk2(s0[0], s0[1]);
    pw[1] = pk2(s0[2], s0[3]);
    pw[2] = pk2(s1[0], s1[1]);
    pw[3] = pk2(s1[2], s1[3]);
    const bf16x8 pfrag = __builtin_bit_cast(bf16x8, pw);
    __builtin_amdgcn_sched_barrier(0);

    // [E] PV: batched asm reads, counted lgkm
    bf16x8 v0, v1, v2, v3, v4, v5, v6, v7;
    {
      lptr vB = vb0 + buf * 4096;
      DSR(v0, vB, "0");
      DSR(v1, vB, "1024");
      DSR(v2, vB, "2048");
      DSR(v3, vB, "3072");
      DSR(v4, vB, "4096");
      DSR(v5, vB, "5120");
      DSR(v6, vB, "6144");
      DSR(v7, vB, "7168");
    }
    asm volatile("s_waitcnt lgkmcnt(4)" ::: "memory");
    __builtin_amdgcn_sched_barrier(0);
    __builtin_amdgcn_s_setprio(1);
    MFMA16(ctx[0], v0, pfrag); MFMA16(ctx[1], v1, pfrag);
    MFMA16(ctx[2], v2, pfrag); MFMA16(ctx[3], v3, pfrag);
    __builtin_amdgcn_sched_barrier(0);
    asm volatile("s_waitcnt lgkmcnt(0)" ::: "memory");
    __builtin_amdgcn_sched_barrier(0);
    MFMA16(ctx[4], v4, pfrag); MFMA16(ctx[5], v5, pfrag);
    MFMA16(ctx[6], v6, pfrag); MFMA16(ctx[7], v7, pfrag);
    __builtin_amdgcn_s_setprio(0);
    __builtin_amdgcn_sched_barrier(0);

    // [F] all reads of buf retired -> next tile may overwrite buf^1's counterpart
    __builtin_amdgcn_s_barrier();
    __builtin_amdgcn_sched_barrier(0);
  }

  // epilogue: d = dt*16 + g4*4 + j
  const float linv = 1.f / l_run;
  u16* crow = Cb + (size_t)qbase * HIDDEN;
#pragma unroll
  for (int dt = 0; dt < 8; dt++) {
    u16x4 o;
#pragma unroll
    for (int j = 0; j < 4; j++) o[j] = f2bf(ctx[dt][j] * linv);
    *(u16x4*)&crow[dt * 16 + g4 * 4] = o;
  }
}

// ---------------- launch ----------------
extern "C" void kernel_launch(void* const* d_in, const int* in_sizes, int n_in,
                              void* d_out, int out_size, void* d_ws, size_t ws_size,
                              hipStream_t stream) {
  (void)in_sizes; (void)n_in; (void)out_size; (void)ws_size;
  const float* x  = (const float*)d_in[0];
  const float* wq = (const float*)d_in[1];
  const float* bq = (const float*)d_in[2];
  const float* wk = (const float*)d_in[3];
  const float* bk = (const float*)d_in[4];
  const float* wv = (const float*)d_in[5];
  const float* bv = (const float*)d_in[6];
  const float* wo = (const float*)d_in[7];
  const float* bo = (const float*)d_in[8];

  const size_t NX = (size_t)BATCH * SEQ * HIDDEN;   // 8.39M
  const size_t NW = (size_t)HIDDEN * HIDDEN;        // 4.19M
  u16* xb   = (u16*)d_ws;            // [NX]
  u16* wqb  = xb  + NX;              // [3NW] contiguous Wq|Wk|Wv
  u16* wkb  = wqb + NW;
  u16* wvb  = wkb + NW;
  u16* wob  = wvb + NW;              // [NW]
  u16* qk   = wob + NW;              // [M,4096] fused Q|K
  u16* vtb  = qk  + 2 * NX;          // [B*H, D, S]
  u16* ctxb = xb;                    // x dead after projections

  cvt_kernel<<<2048, 256, 0, stream>>>(x, xb, (int)(NX / 4));
  cvt4_kernel<<<dim3(512, 4), 256, 0, stream>>>(wq, wk, wv, wo, wqb, wkb, wvb, wob, (int)(NW / 4));

  // 1/sqrt(128) * log2(e): scores in log2 units
  const float qscale = 0.12751744174240807f;
  gemm_qkv<<<512, 512, 0, stream>>>(xb, wqb, bq, bk, bv, qk, vtb, qscale);

  attn_kernel<<<1024, 256, 0, stream>>>(qk, vtb, ctxb);

  gemm_bt<<<512, 256, 0, stream>>>(ctxb, wob, bo, (float*)d_out, BATCH * SEQ, HIDDEN, HIDDEN);
}

// Round 5
// 277.772 us; speedup vs baseline: 1.1745x; 1.0366x over previous
//
#include <hip/hip_runtime.h>

typedef unsigned short u16;
typedef unsigned int   u32;
typedef float  f32x4   __attribute__((ext_vector_type(4)));
typedef __bf16 bf16x8  __attribute__((ext_vector_type(8)));
typedef u16    u16x8   __attribute__((ext_vector_type(8)));
typedef u16    u16x4   __attribute__((ext_vector_type(4)));
typedef u32    u32x2   __attribute__((ext_vector_type(2)));
typedef u32    u32x4   __attribute__((ext_vector_type(4)));

#define HIDDEN 2048
#define SEQ    2048
#define NHEADS 16
#define HD     128
#define BATCH  2
#define QSTR   4096   // fused Q|K row stride

typedef const __attribute__((address_space(3))) u16* lptr;

__device__ __forceinline__ u16 f2bf(float f) {
  u32 u = __builtin_bit_cast(u32, f);
  u += 0x7FFFu + ((u >> 16) & 1u);          // RNE
  return (u16)(u >> 16);
}
__device__ __forceinline__ u32 pk2(float a, float b) {
  __bf16 x = (__bf16)a, y = (__bf16)b;
  return (u32)__builtin_bit_cast(u16, x) | ((u32)__builtin_bit_cast(u16, y) << 16);
}
__device__ __forceinline__ bf16x8 ld_frag(const u16* p) {
  return __builtin_bit_cast(bf16x8, *(const u32x4*)p);
}
__device__ __forceinline__ void gload_lds16(const u16* g, u16* l) {
  __builtin_amdgcn_global_load_lds((const __attribute__((address_space(1))) u32*)g,
                                   (__attribute__((address_space(3))) u32*)l, 16, 0, 0);
}

// inline-asm LDS read: compiler inserts no auto-waits; we count lgkmcnt manually.
#define DSR(dst, base, lit) \
  asm volatile("ds_read_b128 %0, %1 offset:" lit : "=v"(dst) : "v"(base))

#define MFMA16(d, a, b) d = __builtin_amdgcn_mfma_f32_16x16x32_bf16(a, b, d, 0, 0, 0)

// ---------------- fp32 -> bf16 convert ----------------
__global__ __launch_bounds__(256) void cvt_kernel(const float* __restrict__ src,
                                                  u16* __restrict__ dst, int n4) {
  int stride = gridDim.x * blockDim.x;
  for (int i = blockIdx.x * blockDim.x + threadIdx.x; i < n4; i += stride) {
    f32x4 v = ((const f32x4*)src)[i];
    u16x4 o;
    o[0] = f2bf(v[0]); o[1] = f2bf(v[1]); o[2] = f2bf(v[2]); o[3] = f2bf(v[3]);
    *(u16x4*)(dst + (size_t)i * 4) = o;
  }
}

__global__ __launch_bounds__(256) void cvt4_kernel(
    const float* __restrict__ s0, const float* __restrict__ s1,
    const float* __restrict__ s2, const float* __restrict__ s3,
    u16* __restrict__ o0, u16* __restrict__ o1,
    u16* __restrict__ o2, u16* __restrict__ o3, int n4) {
  const float* src = (blockIdx.y == 0) ? s0 : (blockIdx.y == 1) ? s1 : (blockIdx.y == 2) ? s2 : s3;
  u16* dst = (blockIdx.y == 0) ? o0 : (blockIdx.y == 1) ? o1 : (blockIdx.y == 2) ? o2 : o3;
  int stride = gridDim.x * blockDim.x;
  for (int i = blockIdx.x * blockDim.x + threadIdx.x; i < n4; i += stride) {
    f32x4 v = ((const f32x4*)src)[i];
    u16x4 o;
    o[0] = f2bf(v[0]); o[1] = f2bf(v[1]); o[2] = f2bf(v[2]); o[3] = f2bf(v[3]);
    *(u16x4*)(dst + (size_t)i * 4) = o;
  }
}

// ---------------- fused QKV projection: 256Mx192N tile, BK=64, 8-wave, asm-counted pipeline ----------------
__global__ __launch_bounds__(512, 2) void gemm_qkv(
    const u16* __restrict__ A, const u16* __restrict__ Bt,
    const float* __restrict__ bq, const float* __restrict__ bk,
    const float* __restrict__ bv,
    u16* __restrict__ qk, u16* __restrict__ vtb, float qscale)
{
  __shared__ __attribute__((aligned(16))) u16 As[2][16384];  // 64 KiB
  __shared__ __attribute__((aligned(16))) u16 Bs[2][12288];  // 48 KiB

  const int tid  = threadIdx.x;
  const int lane = tid & 63;
  const int wave = tid >> 6;
  const int l15  = lane & 15;
  const int g    = lane >> 4;
  const int wm   = wave >> 2;            // 0..1 (M half, 128 rows)
  const int wn   = wave & 3;             // 0..3 (N quarter, 48 cols)

  // grid 512 = 8 XCD * (4 Ntiles * 16 Mtiles); bijective, 4 B-panels (3MB) L2-resident per XCD
  const int id  = blockIdx.x;
  const int xcd = id & 7;
  const int c   = id >> 3;               // 0..63
  const int tileN = (xcd * 4 + (c >> 4)) * 192;
  const int tileM = (c & 15) << 8;

  // staging: thread covers row (tid>>3) of each 64-row round, chunk (tid&7)
  const int srow = tid >> 3;
  const int gch8 = ((tid & 7) ^ (srow & 7)) * 8;     // pre-swizzled global chunk
  const u16* agp = A  + (size_t)(tileM + srow) * HIDDEN + gch8;
  const u16* bgp = Bt + (size_t)(tileN + srow) * HIDDEN + gch8;
  u16* asp = (u16*)&As[0][0] + tid * 8;
  u16* bsp = (u16*)&Bs[0][0] + tid * 8;

  auto stage = [&](int buf, int ko) {
    u16* ad = asp + buf * 16384;
    u16* bd = bsp + buf * 12288;
#pragma unroll
    for (int r = 0; r < 4; ++r)
      gload_lds16(agp + (size_t)r * 64 * HIDDEN + ko, ad + r * 4096);
#pragma unroll
    for (int r = 0; r < 3; ++r)
      gload_lds16(bgp + (size_t)r * 64 * HIDDEN + ko, bd + r * 4096);
  };

  // fragment read bases (asm, byte offsets in literals): row stride 16 rows = 2048 B
  const int sw = l15 & 7;
  const int c0 = (g ^ sw) * 8;           // k0 chunk (elements)
  const int c1 = ((g ^ sw) ^ 4) * 8;     // k1 chunk
  lptr aT = (lptr)&As[0][0] + (size_t)(wm * 128 + l15) * 64;
  lptr bT = (lptr)&Bs[0][0] + (size_t)(wn * 48 + l15) * 64;

  f32x4 acc[8][3] = {};
  bf16x8 Xa[8], Xb[3], Ya[8], Yb[3];

#define ISSUE_SET(Sa, Sb, ab, bb)      \
  DSR(Sa[0], ab, "0");                 \
  DSR(Sa[1], ab, "2048");              \
  DSR(Sa[2], ab, "4096");              \
  DSR(Sa[3], ab, "6144");              \
  DSR(Sa[4], ab, "8192");              \
  DSR(Sa[5], ab, "10240");             \
  DSR(Sa[6], ab, "12288");             \
  DSR(Sa[7], ab, "14336");             \
  DSR(Sb[0], bb, "0");                 \
  DSR(Sb[1], bb, "2048");              \
  DSR(Sb[2], bb, "4096");

#define MFMA24(Sa, Sb)                                                                    \
  _Pragma("unroll")                                                                       \
  for (int mf = 0; mf < 8; ++mf) {                                                        \
    _Pragma("unroll")                                                                     \
    for (int nf = 0; nf < 3; ++nf)                                                        \
      acc[mf][nf] = __builtin_amdgcn_mfma_f32_16x16x32_bf16(Sa[mf], Sb[nf], acc[mf][nf], 0, 0, 0); \
  }

  // ---- prologue: stage tiles 0,1; wait tile0; issue X=(buf0,k0)
  stage(0, 0);
  stage(1, 64);
  asm volatile("s_waitcnt vmcnt(7)" ::: "memory");
  __builtin_amdgcn_s_barrier();
  __builtin_amdgcn_sched_barrier(0);
  {
    lptr ab = aT + c0;
    lptr bb = bT + c0;
    ISSUE_SET(Xa, Xb, ab, bb)
  }

#pragma unroll 2
  for (int t = 0; t < 32; ++t) {
    const int cur = t & 1;
    lptr aC = aT + cur * 16384;
    lptr bC = bT + cur * 12288;
    // [1] Y <- (cur, k1)
    {
      lptr ab = aC + c1;
      lptr bb = bC + c1;
      ISSUE_SET(Ya, Yb, ab, bb)
    }
    // [2] X ready (Y in flight)
    asm volatile("s_waitcnt lgkmcnt(11)" ::: "memory");
    __builtin_amdgcn_sched_barrier(0);
    __builtin_amdgcn_s_setprio(1);
    MFMA24(Xa, Xb)
    __builtin_amdgcn_s_setprio(0);
    // [3] Y ready
    asm volatile("s_waitcnt lgkmcnt(0)" ::: "memory");
    __builtin_amdgcn_sched_barrier(0);
    __builtin_amdgcn_s_setprio(1);
    MFMA24(Ya, Yb)
    __builtin_amdgcn_s_setprio(0);
    // [4] all waves finished reading cur
    __builtin_amdgcn_s_barrier();
    __builtin_amdgcn_sched_barrier(0);
    // [5] stage t+2 -> cur ; [6] t+1 landed for everyone
    if (t < 30) {
      stage(cur, (t + 2) * 64);
      asm volatile("s_waitcnt vmcnt(7)" ::: "memory");
    } else {
      asm volatile("s_waitcnt vmcnt(0)" ::: "memory");
    }
    __builtin_amdgcn_s_barrier();
    __builtin_amdgcn_sched_barrier(0);
    // [7] X <- (nxt, k0)
    if (t < 31) {
      lptr ab = aT + (cur ^ 1) * 16384 + c0;
      lptr bb = bT + (cur ^ 1) * 12288 + c0;
      ISSUE_SET(Xa, Xb, ab, bb)
    }
  }

  // ---------- epilogue: Q|K -> qk (scaled, biased), V -> transposed vtb
#pragma unroll
  for (int mi = 0; mi < 8; ++mi) {
#pragma unroll
    for (int ni = 0; ni < 3; ++ni) {
      const int gcb = tileN + wn * 48 + ni * 16;
      const int seg = gcb >> 11;                     // 0=Q 1=K 2=V
      const int gc  = gcb + l15;
      const float bvv = ((seg == 0) ? bq : (seg == 1) ? bk : bv)[gc & 2047];
      if (seg < 2) {
        const float scl = (seg == 0) ? qscale : 1.f;
#pragma unroll
        for (int j = 0; j < 4; ++j) {
          const int gr = tileM + wm * 128 + mi * 16 + g * 4 + j;
          qk[(size_t)gr * QSTR + gc] = f2bf((acc[mi][ni][j] + bvv) * scl);
        }
      } else {
        const int dglob = gc - 4096;
        const int hh = dglob >> 7, dd = dglob & 127;
        const int srow0 = tileM + wm * 128 + mi * 16 + g * 4;
        const int bb = srow0 >> 11, ss = srow0 & 2047;
        u16x4 o;
#pragma unroll
        for (int j = 0; j < 4; ++j) o[j] = f2bf(acc[mi][ni][j] + bvv);
        *(u16x4*)(vtb + ((size_t)((bb * NHEADS + hh) * HD + dd)) * SEQ + ss) = o;
      }
    }
  }
#undef ISSUE_SET
#undef MFMA24
}

// ---------------- C = A[M,K] * Bt[N,K]^T + bias (output projection, proven 2-phase) ----------------
__global__ __launch_bounds__(256, 2) void gemm_bt(
    const u16* __restrict__ A, const u16* __restrict__ Bt,
    const float* __restrict__ bias, float* __restrict__ Cout,
    int M, int N, int K)
{
  __shared__ __attribute__((aligned(16))) u16 As[128 * 32];
  __shared__ __attribute__((aligned(16))) u16 Bs[128 * 32];
  const int tid  = threadIdx.x;
  const int lane = tid & 63;
  const int wave = tid >> 6;

  const int nbx   = N >> 7;
  const int nby   = M >> 7;
  const int id    = blockIdx.x;
  const int xcd   = id & 7;
  const int c     = id >> 3;
  const int cpx   = nbx >> 3;
  const int tileN = (xcd * cpx + c / nby) << 7;
  const int tileM = (c % nby) << 7;

  const int g = lane >> 4, r = lane & 15;

  const int srow = lane >> 2;
  const int scol = (lane & 3) * 8;
  const u16* ag0 = A  + (size_t)(tileM + wave * 16 + srow) * K + scol;
  const u16* ag1 = ag0 + (size_t)64 * K;
  const u16* bg0 = Bt + (size_t)(tileN + wave * 16 + srow) * K + scol;
  const u16* bg1 = bg0 + (size_t)64 * K;
  u16* as0 = &As[wave * 512];
  u16* as1 = &As[(wave + 4) * 512];
  u16* bs0 = &Bs[wave * 512];
  u16* bs1 = &Bs[(wave + 4) * 512];

  const int wm = wave >> 1, wn = wave & 1;
  const u16* afp = &As[(wm * 64 + r) * 32 + g * 8];
  const u16* bfp = &Bs[(wn * 64 + r) * 32 + g * 8];

  f32x4 acc[4][4] = {};

  for (int kt = 0; kt < K; kt += 32) {
    __syncthreads();
    gload_lds16(ag0 + kt, as0);
    gload_lds16(ag1 + kt, as1);
    gload_lds16(bg0 + kt, bs0);
    gload_lds16(bg1 + kt, bs1);
    __syncthreads();
    bf16x8 af[4], bf[4];
#pragma unroll
    for (int mi = 0; mi < 4; mi++) af[mi] = ld_frag(afp + mi * 512);
#pragma unroll
    for (int ni = 0; ni < 4; ni++) bf[ni] = ld_frag(bfp + ni * 512);
#pragma unroll
    for (int mi = 0; mi < 4; mi++)
#pragma unroll
      for (int ni = 0; ni < 4; ni++)
        acc[mi][ni] = __builtin_amdgcn_mfma_f32_16x16x32_bf16(af[mi], bf[ni], acc[mi][ni], 0, 0, 0);
  }

#pragma unroll
  for (int mi = 0; mi < 4; mi++) {
#pragma unroll
    for (int ni = 0; ni < 4; ni++) {
      const int gc = tileN + wn * 64 + ni * 16 + r;
      const float bv = bias[gc];
#pragma unroll
      for (int j = 0; j < 4; j++) {
        const int gr = tileM + wm * 64 + mi * 16 + g * 4 + j;
        Cout[(size_t)gr * N + gc] = acc[mi][ni][j] + bv;
      }
    }
  }
}

// ---------------- flash attention: KVBLK=64, 32 q/wave (2 groups), 4 waves, grid 512 ----------------
// Fat tile: 64 MFMA per wave-tile amortizes softmax shuffles + barriers (4x round-4 density).
// K LDS [64][128] unit-swizzled (proven key, invariant across all 4 ni-blocks);
// V LDS [128][64] chunk c stored at c^(d&7) via pre-swizzled global source -> 2-way banks.
__global__ __launch_bounds__(256, 2) void attn_kernel(
    const u16* __restrict__ QKg, const u16* __restrict__ Vtg, u16* __restrict__ Ctx)
{
  __shared__ __attribute__((aligned(16))) u16 Ks[2][64 * 128]; // 32 KiB
  __shared__ __attribute__((aligned(16))) u16 Vs[2][128 * 64]; // 32 KiB

  const int tid  = threadIdx.x;
  const int lane = tid & 63;
  const int wave = tid >> 6;
  const int g4   = lane >> 4;
  const int l15  = lane & 15;

  // XCD-chunked bijective swizzle (512 = 8*64): 16 blocks per (b,h), 128-q tiles
  const int wg = ((blockIdx.x & 7) << 6) + (blockIdx.x >> 3);
  const int bh = wg >> 4;
  const int qt = wg & 15;
  const int b  = bh >> 4, h = bh & 15;

  const u16* Qb  = QKg + (size_t)b * SEQ * QSTR + (size_t)h * HD;
  const u16* Kb  = Qb + 2048;
  const u16* Vth = Vtg + (size_t)bh * HD * SEQ;
  u16* Cb = Ctx + (size_t)b * SEQ * HIDDEN + (size_t)h * HD;

  const int qbase = qt * 128 + wave * 32 + l15;   // q-group qs adds qs*16

  // Q fragments (B-operand): Q[q][dc*32 + g4*8 + e], 2 q-groups
  bf16x8 qf[2][4];
#pragma unroll
  for (int qs = 0; qs < 2; qs++)
#pragma unroll
    for (int dc = 0; dc < 4; dc++)
      qf[qs][dc] = ld_frag(Qb + (size_t)(qbase + qs * 16) * QSTR + dc * 32 + g4 * 8);

  // K A-frag addressing: physical row(ni) = (ni>>1)*32 + kvp0 + (ni&1)*4
  // unit(dc) = (dc*4+g4)^msw  ->  base_even/odd + (dc>>1)*128B literal
  const int kvp0 = (l15 >> 2) * 8 + (l15 & 3);
  const int msw  = (l15 & 3) | (((l15 >> 2) & 1) << 2);
  const int msw3 = msw & 3;
  const int mk   = (l15 >> 2) & 1;
  const int kcol = (g4 ^ msw3) * 8;

  lptr ksb = (lptr)&Ks[0][0];
  lptr kE0 = ksb + (kvp0      ) * 128 + kcol + mk * 32;
  lptr kO0 = ksb + (kvp0      ) * 128 + kcol + (1 ^ mk) * 32;
  lptr kE1 = ksb + (kvp0 +   4) * 128 + kcol + mk * 32;
  lptr kO1 = ksb + (kvp0 +   4) * 128 + kcol + (1 ^ mk) * 32;
  lptr kE2 = ksb + (kvp0 +  32) * 128 + kcol + mk * 32;
  lptr kO2 = ksb + (kvp0 +  32) * 128 + kcol + (1 ^ mk) * 32;
  lptr kE3 = ksb + (kvp0 +  36) * 128 + kcol + mk * 32;
  lptr kO3 = ksb + (kvp0 +  36) * 128 + kcol + (1 ^ mk) * 32;

  // V A-frag: row d = dt*16+l15, kv-chunk (h*4+g4)^(d&7); dt -> +2048B literal
  lptr vsb = (lptr)&Vs[0][0];
  lptr vB0 = vsb + l15 * 64 + ((0 * 4 + g4) ^ (l15 & 7)) * 8;
  lptr vB1 = vsb + l15 * 64 + ((1 * 4 + g4) ^ (l15 & 7)) * 8;

  // staging source pointers (4 K + 4 V per thread per tile), kv0 added per tile
  const u16* kg[4];
  const u16* vg[4];
  u16* ksd = (u16*)&Ks[0][0] + tid * 8;
  u16* vsd = (u16*)&Vs[0][0] + tid * 8;
#pragma unroll
  for (int i = 0; i < 4; i++) {
    const int idx = tid + i * 256;
    const int kv = idx >> 4, up = idx & 15;
    const int um = up ^ ((kv & 3) | (((kv >> 3) & 1) << 2));
    kg[i] = Kb + (size_t)kv * QSTR + um * 8;
    const int d = idx >> 3, u = idx & 7;
    const int uv = u ^ (d & 7);
    vg[i] = Vth + (size_t)d * SEQ + uv * 8;
  }

  auto stage = [&](int buf, int kv0) {
    u16* kd = ksd + buf * 8192;
    u16* vd = vsd + buf * 8192;
#pragma unroll
    for (int i = 0; i < 4; i++) gload_lds16(kg[i] + (size_t)kv0 * QSTR, kd + i * 2048);
#pragma unroll
    for (int i = 0; i < 4; i++) gload_lds16(vg[i] + kv0, vd + i * 2048);
  };

  f32x4 ctx[2][8] = {};
  float m_run[2] = {-1e30f, -1e30f};
  float l_run[2] = {0.f, 0.f};

  stage(0, 0);

  const int NT = SEQ / 64;
  for (int t = 0; t < NT; t++) {
    const int buf = t & 1;

    // [A] prefetch next tile; counted wait: own stage(t) landed, stage(t+1) in flight
    if (t + 1 < NT) {
      stage(buf ^ 1, (t + 1) * 64);
      asm volatile("s_waitcnt vmcnt(8)" ::: "memory");
    } else {
      asm volatile("s_waitcnt vmcnt(0)" ::: "memory");
    }
    __builtin_amdgcn_s_barrier();
    __builtin_amdgcn_sched_barrier(0);

    // [C] QK^T: 16 asm K-reads (shared by both q-groups), counted lgkm
    bf16x8 kf[4][4];
    {
      const int bo = buf * 8192;
      lptr e0 = kE0 + bo, o0 = kO0 + bo, e1 = kE1 + bo, o1 = kO1 + bo;
      lptr e2 = kE2 + bo, o2 = kO2 + bo, e3 = kE3 + bo, o3 = kO3 + bo;
      DSR(kf[0][0], e0, "0"); DSR(kf[0][1], o0, "0"); DSR(kf[0][2], e0, "128"); DSR(kf[0][3], o0, "128");
      DSR(kf[1][0], e1, "0"); DSR(kf[1][1], o1, "0"); DSR(kf[1][2], e1, "128"); DSR(kf[1][3], o1, "128");
      DSR(kf[2][0], e2, "0"); DSR(kf[2][1], o2, "0"); DSR(kf[2][2], e2, "128"); DSR(kf[2][3], o2, "128");
      DSR(kf[3][0], e3, "0"); DSR(kf[3][1], o3, "0"); DSR(kf[3][2], e3, "128"); DSR(kf[3][3], o3, "128");
    }
    f32x4 s[2][4] = {};
    asm volatile("s_waitcnt lgkmcnt(8)" ::: "memory");
    __builtin_amdgcn_sched_barrier(0);
    __builtin_amdgcn_s_setprio(1);
#pragma unroll
    for (int ni = 0; ni < 2; ni++)
#pragma unroll
      for (int dc = 0; dc < 4; dc++) {
        MFMA16(s[0][ni], kf[ni][dc], qf[0][dc]);
        MFMA16(s[1][ni], kf[ni][dc], qf[1][dc]);
      }
    __builtin_amdgcn_sched_barrier(0);
    asm volatile("s_waitcnt lgkmcnt(0)" ::: "memory");
    __builtin_amdgcn_sched_barrier(0);
#pragma unroll
    for (int ni = 2; ni < 4; ni++)
#pragma unroll
      for (int dc = 0; dc < 4; dc++) {
        MFMA16(s[0][ni], kf[ni][dc], qf[0][dc]);
        MFMA16(s[1][ni], kf[ni][dc], qf[1][dc]);
      }
    __builtin_amdgcn_s_setprio(0);
    __builtin_amdgcn_sched_barrier(0);

    // [D] online softmax (log2 units); lane owns q (per group), 16 scores:
    // kv' = (ni>>1)*32 + g4*8 + (ni&1)*4 + j
    float pmax[2];
#pragma unroll
    for (int qs = 0; qs < 2; qs++) {
      float m0 = fmaxf(fmaxf(s[qs][0][0], s[qs][0][1]), fmaxf(s[qs][0][2], s[qs][0][3]));
      float m1 = fmaxf(fmaxf(s[qs][1][0], s[qs][1][1]), fmaxf(s[qs][1][2], s[qs][1][3]));
      float m2 = fmaxf(fmaxf(s[qs][2][0], s[qs][2][1]), fmaxf(s[qs][2][2], s[qs][2][3]));
      float m3 = fmaxf(fmaxf(s[qs][3][0], s[qs][3][1]), fmaxf(s[qs][3][2], s[qs][3][3]));
      pmax[qs] = fmaxf(fmaxf(m0, m1), fmaxf(m2, m3));
      pmax[qs] = fmaxf(pmax[qs], __shfl_xor(pmax[qs], 16));
      pmax[qs] = fmaxf(pmax[qs], __shfl_xor(pmax[qs], 32));
    }
    const bool ok0 = (pmax[0] <= m_run[0] + 8.f);
    const bool ok1 = (pmax[1] <= m_run[1] + 8.f);
    if (!__all(ok0 && ok1)) {                     // defer-max (T13)
#pragma unroll
      for (int qs = 0; qs < 2; qs++) {
        const float mn = fmaxf(m_run[qs], pmax[qs]);
        const float corr = exp2f(m_run[qs] - mn);
        m_run[qs] = mn;
        l_run[qs] *= corr;
#pragma unroll
        for (int dt = 0; dt < 8; dt++)
#pragma unroll
          for (int j = 0; j < 4; j++) ctx[qs][dt][j] *= corr;
      }
    }
    bf16x8 pfrag[2][2];
#pragma unroll
    for (int qs = 0; qs < 2; qs++) {
      float ps = 0.f;
#pragma unroll
      for (int ni = 0; ni < 4; ni++)
#pragma unroll
        for (int j = 0; j < 4; j++) {
          const float p = exp2f(s[qs][ni][j] - m_run[qs]);
          s[qs][ni][j] = p;
          ps += p;
        }
      ps += __shfl_xor(ps, 16);
      ps += __shfl_xor(ps, 32);
      l_run[qs] += ps;
#pragma unroll
      for (int hh = 0; hh < 2; hh++) {
        u32x4 pw;
        pw[0] = pk2(s[qs][2 * hh][0], s[qs][2 * hh][1]);
        pw[1] = pk2(s[qs][2 * hh][2], s[qs][2 * hh][3]);
        pw[2] = pk2(s[qs][2 * hh + 1][0], s[qs][2 * hh + 1][1]);
        pw[3] = pk2(s[qs][2 * hh + 1][2], s[qs][2 * hh + 1][3]);
        pfrag[qs][hh] = __builtin_bit_cast(bf16x8, pw);
      }
    }
    __builtin_amdgcn_sched_barrier(0);

    // [E] PV: 16 asm V-reads (shared by both q-groups), counted lgkm
    bf16x8 vf[2][8];
    {
      lptr v0 = vB0 + buf * 8192;
      lptr v1 = vB1 + buf * 8192;
      DSR(vf[0][0], v0, "0");     DSR(vf[0][1], v0, "2048");
      DSR(vf[0][2], v0, "4096");  DSR(vf[0][3], v0, "6144");
      DSR(vf[0][4], v0, "8192");  DSR(vf[0][5], v0, "10240");
      DSR(vf[0][6], v0, "12288"); DSR(vf[0][7], v0, "14336");
      DSR(vf[1][0], v1, "0");     DSR(vf[1][1], v1, "2048");
      DSR(vf[1][2], v1, "4096");  DSR(vf[1][3], v1, "6144");
      DSR(vf[1][4], v1, "8192");  DSR(vf[1][5], v1, "10240");
      DSR(vf[1][6], v1, "12288"); DSR(vf[1][7], v1, "14336");
    }
    asm volatile("s_waitcnt lgkmcnt(8)" ::: "memory");
    __builtin_amdgcn_sched_barrier(0);
    __builtin_amdgcn_s_setprio(1);
#pragma unroll
    for (int dt = 0; dt < 8; dt++) {
      MFMA16(ctx[0][dt], vf[0][dt], pfrag[0][0]);
      MFMA16(ctx[1][dt], vf[0][dt], pfrag[1][0]);
    }
    __builtin_amdgcn_sched_barrier(0);
    asm volatile("s_waitcnt lgkmcnt(0)" ::: "memory");
    __builtin_amdgcn_sched_barrier(0);
#pragma unroll
    for (int dt = 0; dt < 8; dt++) {
      MFMA16(ctx[0][dt], vf[1][dt], pfrag[0][1]);
      MFMA16(ctx[1][dt], vf[1][dt], pfrag[1][1]);
    }
    __builtin_amdgcn_s_setprio(0);
    __builtin_amdgcn_sched_barrier(0);

    // [F] all reads of buf retired -> [A] of next tile may overwrite buf^1
    __builtin_amdgcn_s_barrier();
    __builtin_amdgcn_sched_barrier(0);
  }

  // epilogue: d = dt*16 + g4*4 + j
#pragma unroll
  for (int qs = 0; qs < 2; qs++) {
    const float linv = 1.f / l_run[qs];
    u16* crow = Cb + (size_t)(qbase + qs * 16) * HIDDEN;
#pragma unroll
    for (int dt = 0; dt < 8; dt++) {
      u16x4 o;
#pragma unroll
      for (int j = 0; j < 4; j++) o[j] = f2bf(ctx[qs][dt][j] * linv);
      *(u16x4*)&crow[dt * 16 + g4 * 4] = o;
    }
  }
}

// ---------------- launch ----------------
extern "C" void kernel_launch(void* const* d_in, const int* in_sizes, int n_in,
                              void* d_out, int out_size, void* d_ws, size_t ws_size,
                              hipStream_t stream) {
  (void)in_sizes; (void)n_in; (void)out_size; (void)ws_size;
  const float* x  = (const float*)d_in[0];
  const float* wq = (const float*)d_in[1];
  const float* bq = (const float*)d_in[2];
  const float* wk = (const float*)d_in[3];
  const float* bk = (const float*)d_in[4];
  const float* wv = (const float*)d_in[5];
  const float* bv = (const float*)d_in[6];
  const float* wo = (const float*)d_in[7];
  const float* bo = (const float*)d_in[8];

  const size_t NX = (size_t)BATCH * SEQ * HIDDEN;   // 8.39M
  const size_t NW = (size_t)HIDDEN * HIDDEN;        // 4.19M
  u16* xb   = (u16*)d_ws;            // [NX]
  u16* wqb  = xb  + NX;              // [3NW] contiguous Wq|Wk|Wv
  u16* wkb  = wqb + NW;
  u16* wvb  = wkb + NW;
  u16* wob  = wvb + NW;              // [NW]
  u16* qk   = wob + NW;              // [M,4096] fused Q|K
  u16* vtb  = qk  + 2 * NX;          // [B*H, D, S]
  u16* ctxb = xb;                    // x dead after projections

  cvt_kernel<<<2048, 256, 0, stream>>>(x, xb, (int)(NX / 4));
  cvt4_kernel<<<dim3(512, 4), 256, 0, stream>>>(wq, wk, wv, wo, wqb, wkb, wvb, wob, (int)(NW / 4));

  // 1/sqrt(128) * log2(e): scores in log2 units
  const float qscale = 0.12751744174240807f;
  gemm_qkv<<<512, 512, 0, stream>>>(xb, wqb, bq, bk, bv, qk, vtb, qscale);

  attn_kernel<<<512, 256, 0, stream>>>(qk, vtb, ctxb);

  gemm_bt<<<512, 256, 0, stream>>>(ctxb, wob, bo, (float*)d_out, BATCH * SEQ, HIDDEN, HIDDEN);
}